// Round 12
// baseline (548.566 us; speedup 1.0000x reference)
//
#include <hip/hip_runtime.h>
#include <math.h>

#define N_NODES 50000
#define N_EDGES 800000
#define N_GRAPHS 512
#define D 64
#define DE 32
#define NB_SCAN 196            // ceil(50000/256)
#define NSTR 136               // NT LDS row stride (ushorts), 272B = 16B-aligned
#define NB_SCAT 3125           // scatter blocks (800K/256)
#define NB_FUSED 4689          // 3 * 1563: role = blockIdx % 3 (2 -> NT)
#define NB_EDGE 1563           // edge blocks: 6250 waves x 128 edges

// ---------------------------------------------------------------------------
// R20: R19 showed the permutation cost is CONSERVED (random eaS write once
// vs random eaP read twice — net flat 442). Revert to R18 dataflow (sorted
// eaS, scatter pays the permutation ONCE on the write side). Edge-kernel
// compute attack:
//  * dst bf16-unpack hoisted to dst-change (was 8 upk/edge, dst constant
//    over ~16-edge runs)
//  * 2x64 consecutive edges per wave (6250 waves): run-length state + dst
//    cache persist across group boundary, W-frags amortized, longer waves
//    for steadier residency (occ was 20-27% vs 62% VGPR cap)
//  * scatter random stores use __builtin_nontemporal_store (full-line data,
//    never re-read by writer) to avoid RFO fetches
// R17 lesson: atomics need line-SPREAD (h1/h2 50K rows, never pooled's 512).
// R14 atomic law: flush = 4 atomics x 16 lanes contiguous 64B = 1 line/inst.
//
// MFMA 16x16x32 bf16 fragment maps (m89/m120-verified):
//   A[m][k]: m = lane&15, k = (lane>>4)*8 + i
//   B[k][n]: n = lane&15, k = (lane>>4)*8 + i
//   C/D    : col n = lane&15, row m = (lane>>4)*4 + reg
// Edge A-row permutation: row m of MFMA tt <- edge base + 16*(m>>2)+(m&3)+4tt
//   => quad q processes edges base+16q .. base+16q+15 IN ORDER.
// Edge column map: j = 16*jb + n16 (contiguous-flush).
// ---------------------------------------------------------------------------

typedef __attribute__((ext_vector_type(8))) short short8;
typedef __attribute__((ext_vector_type(4))) float floatx4;
typedef __attribute__((ext_vector_type(4))) unsigned uix4;
union Frag { short8 s; unsigned u[4]; };
union U4   { uint4 v; unsigned u[4]; };

__device__ inline unsigned pk_bf16(float lo, float hi) {
    unsigned a = __float_as_uint(lo);
    unsigned b = __float_as_uint(hi);
    a = (a + 0x7FFFu + ((a >> 16) & 1u)) >> 16;
    b = (b + 0x7FFFu + ((b >> 16) & 1u)) >> 16;
    return a | (b << 16);
}
__device__ inline unsigned short bf16_1(float v) {
    unsigned a = __float_as_uint(v);
    return (unsigned short)((a + 0x7FFFu + ((a >> 16) & 1u)) >> 16);
}
__device__ inline float upk(unsigned u16) { return __uint_as_float(u16 << 16); }

// ---- setup: pack_W (blocks 0..9) + zero deg (10..205) + zero pooled -------
__global__ __launch_bounds__(256) void setup_kernel(
    const float* __restrict__ Wf1, const float* __restrict__ Ws1,
    const float* __restrict__ Wf2, const float* __restrict__ Ws2,
    uint4* __restrict__ WpkNT, uint4* __restrict__ WpkE,
    int* __restrict__ deg, float* __restrict__ pooled)
{
    const int b = blockIdx.x;
    if (b >= 206) {                       // zero pooled: 128 blocks
        int i = (b - 206) * 256 + threadIdx.x;
        if (i < N_GRAPHS * D) pooled[i] = 0.0f;
        return;
    }
    if (b >= 10) {                        // zero deg: 196 blocks
        int i = (b - 10) * 256 + threadIdx.x;
        if (i < N_NODES) deg[i] = 0;
        return;
    }
    const int layer = b / 5;
    const float* Wf = layer ? Wf2 : Wf1;
    const float* Ws = layer ? Ws2 : Ws1;
    const int i = (b % 5) * 256 + threadIdx.x;   // 0..1279
    if (i < 1024) {
        const int p    = i >> 9;
        const int cbi  = (i >> 6) & 7;
        const int l    = i & 63;
        const int n16  = l & 15, quad = l >> 4, kc = quad * 8;
        const int col  = cbi * 16 + n16;
        const int j    = col >> 1;
        const float* Wsel = (col & 1) ? Ws : Wf;
        const int rbase = p * 64;
        U4 b0, b1;
#pragma unroll
        for (int pp = 0; pp < 4; ++pp) {
            b0.u[pp] = pk_bf16(Wsel[(rbase + kc + 2 * pp) * 64 + j],
                               Wsel[(rbase + kc + 2 * pp + 1) * 64 + j]);
            b1.u[pp] = pk_bf16(Wsel[(rbase + 32 + kc + 2 * pp) * 64 + j],
                               Wsel[(rbase + 32 + kc + 2 * pp + 1) * 64 + j]);
        }
        uint4* o = WpkNT + ((size_t)layer * 1024 + i) * 2;
        o[0] = b0.v; o[1] = b1.v;
    } else if (i < 1280) {
        const int k  = i - 1024;
        const int jb = k >> 6;
        const int l  = k & 63;
        const int n16 = l & 15, quad = l >> 4, c0 = quad * 8;
        const int j = jb * 16 + n16;             // contiguous-flush map
        U4 bf_, bs_;
#pragma unroll
        for (int pp = 0; pp < 4; ++pp) {
            bf_.u[pp] = pk_bf16(Wf[(128 + c0 + 2 * pp) * 64 + j],
                                Wf[(128 + c0 + 2 * pp + 1) * 64 + j]);
            bs_.u[pp] = pk_bf16(Ws[(128 + c0 + 2 * pp) * 64 + j],
                                Ws[(128 + c0 + 2 * pp + 1) * 64 + j]);
        }
        uint4* o = WpkE + ((size_t)layer * 256 + k) * 2;
        o[0] = bf_.v; o[1] = bs_.v;
    }
}

// ---- hist (+rank): scatter needs no atomic of its own ----------------------
__global__ __launch_bounds__(256) void hist_kernel(
    const int* __restrict__ ei, int* __restrict__ deg, int* __restrict__ rank)
{
    int e = blockIdx.x * 256 + threadIdx.x;
    rank[e] = atomicAdd(&deg[ei[N_EDGES + e]], 1);
}

__global__ __launch_bounds__(256) void scan1(
    const int* __restrict__ deg, int* __restrict__ off, int* __restrict__ tsum)
{
    __shared__ int s[256];
    int i = blockIdx.x * 256 + threadIdx.x;
    s[threadIdx.x] = (i < N_NODES) ? deg[i] : 0;
    __syncthreads();
    if (threadIdx.x == 0) {
        int run = 0;
        for (int k = 0; k < 256; ++k) { int t = s[k]; s[k] = run; run += t; }
        tsum[blockIdx.x] = run;
    }
    __syncthreads();
    if (i < N_NODES) off[i] = s[threadIdx.x];
}

// scan2+scan3 fused: every block redundantly computes its exclusive prefix
__global__ __launch_bounds__(256) void scan23(
    int* __restrict__ off, const int* __restrict__ tsum)
{
    __shared__ int pfx;
    if (threadIdx.x == 0) {
        int run = 0;
        for (int k = 0; k < (int)blockIdx.x; ++k) run += tsum[k];
        pfx = run;
    }
    __syncthreads();
    int i = blockIdx.x * 256 + threadIdx.x;
    if (i < N_NODES) off[i] += pfx;
    if (i == N_NODES) off[i] = N_EDGES;
}

// ---- FUSED: scatter_pack + node_transform L1, roles INTERLEAVED -----------
// blockIdx % 3 == 2 -> NT (1563 blocks); else scatter (3126 slots, 3125 used)
__global__ __launch_bounds__(256) void fused_scatter_nt(
    const int* __restrict__ ei, const int* __restrict__ off,
    const int* __restrict__ rank, const float* __restrict__ ea,
    unsigned short* __restrict__ eaS, int2* __restrict__ sd_sorted,
    const float* __restrict__ H,
    const float* __restrict__ bf, const float* __restrict__ bs,
    const uint4* __restrict__ Wpk,
    unsigned short* __restrict__ Tdst, unsigned short* __restrict__ Tsrc,
    float* __restrict__ hinit)
{
    __shared__ unsigned short lt[4][16 * NSTR];
    const int k = blockIdx.x;

    if ((k % 3) != 2) {
        const int sid = k - (k / 3);
        if (sid >= NB_SCAT) return;
        int e = sid * 256 + threadIdx.x;
        int s = ei[e];
        int d = ei[N_EDGES + e];
        int pos = off[d] + rank[e];
        // random stores: non-temporal (full-line data, never re-read here)
        long long sd = ((long long)d << 32) | (unsigned)s;
        __builtin_nontemporal_store(sd, (long long*)&sd_sorted[pos]);

        const float4* src4 = (const float4*)(ea + (size_t)e * 32);
        uix4* dst16 = (uix4*)(eaS + (size_t)pos * 32);
#pragma unroll
        for (int q = 0; q < 2; ++q) {
            float4 v0 = src4[4 * q + 0];
            float4 v1 = src4[4 * q + 1];
            float4 v2 = src4[4 * q + 2];
            float4 v3 = src4[4 * q + 3];
            uix4 o0;
            o0.x = pk_bf16(v0.x, v0.y); o0.y = pk_bf16(v0.z, v0.w);
            o0.z = pk_bf16(v1.x, v1.y); o0.w = pk_bf16(v1.z, v1.w);
            uix4 o1;
            o1.x = pk_bf16(v2.x, v2.y); o1.y = pk_bf16(v2.z, v2.w);
            o1.z = pk_bf16(v3.x, v3.y); o1.w = pk_bf16(v3.z, v3.w);
            __builtin_nontemporal_store(o0, dst16 + 2 * q);
            __builtin_nontemporal_store(o1, dst16 + 2 * q + 1);
        }
        return;
    }

    const int lane = threadIdx.x & 63;
    const int wid  = threadIdx.x >> 6;
    const int n16  = lane & 15;
    const int quad = lane >> 4;
    const int kc   = quad * 8;
    unsigned short* L = lt[wid];

    const int gid = (k / 3) * 4 + wid;
    const int NW  = (N_NODES / 16) * 2;
    if (gid >= NW) return;
    const int ntile = gid >> 1;
    const int part  = gid & 1;
    unsigned short* Tout = part ? Tsrc : Tdst;

    const float* hrow = H + (size_t)(ntile * 16 + n16) * D;
    float4 q0 = *(const float4*)(hrow + kc);
    float4 q1 = *(const float4*)(hrow + kc + 4);
    float4 q2 = *(const float4*)(hrow + 32 + kc);
    float4 q3 = *(const float4*)(hrow + 32 + kc + 4);
    Frag a0, a1;
    a0.u[0] = pk_bf16(q0.x, q0.y); a0.u[1] = pk_bf16(q0.z, q0.w);
    a0.u[2] = pk_bf16(q1.x, q1.y); a0.u[3] = pk_bf16(q1.z, q1.w);
    a1.u[0] = pk_bf16(q2.x, q2.y); a1.u[1] = pk_bf16(q2.z, q2.w);
    a1.u[2] = pk_bf16(q3.x, q3.y); a1.u[3] = pk_bf16(q3.z, q3.w);

    if (part == 0) {
        float4* hp = (float4*)(hinit + (size_t)(ntile * 16 + n16) * D);
        hp[quad * 2]     = q0;
        hp[quad * 2 + 1] = q1;
        hp[8 + quad * 2] = q2;
        hp[9 + quad * 2] = q3;
    }

#pragma unroll
    for (int cbi = 0; cbi < 8; ++cbi) {
        const int col   = cbi * 16 + n16;
        const int sflag = col & 1;
        const int j     = col >> 1;

        Frag b0, b1;
        {
            const uint4* bp = Wpk + ((size_t)(part * 512 + cbi * 64 + lane)) * 2;
            *(uint4*)&b0 = bp[0];
            *(uint4*)&b1 = bp[1];
        }
        float bias = 0.0f;
        if (part == 0) bias = sflag ? bs[j] : bf[j];

        floatx4 acc = {bias, bias, bias, bias};
        acc = __builtin_amdgcn_mfma_f32_16x16x32_bf16(a0.s, b0.s, acc, 0, 0, 0);
        acc = __builtin_amdgcn_mfma_f32_16x16x32_bf16(a1.s, b1.s, acc, 0, 0, 0);

#pragma unroll
        for (int r = 0; r < 4; ++r)
            L[(quad * 4 + r) * NSTR + col] = bf16_1(acc[r]);
    }

#pragma unroll
    for (int it = 0; it < 4; ++it) {
        const int node_l = it * 4 + quad;
        const int c8     = n16 * 8;
        uint4 v = *(const uint4*)(L + node_l * NSTR + c8);
        *(uint4*)(Tout + (size_t)(ntile * 16 + node_l) * 128 + c8) = v;
    }
}

// ---- node transform (standalone, layer 2) ---------------------------------
__global__ __launch_bounds__(256) void node_transform_mfma(
    const float* __restrict__ H,
    const float* __restrict__ bf,
    const float* __restrict__ bs,
    const uint4* __restrict__ Wpk,
    unsigned short* __restrict__ Tdst,
    unsigned short* __restrict__ Tsrc,
    float* __restrict__ hinit)
{
    __shared__ unsigned short lt[4][16 * NSTR];
    const int lane = threadIdx.x & 63;
    const int wid  = threadIdx.x >> 6;
    const int n16  = lane & 15;
    const int quad = lane >> 4;
    const int kc   = quad * 8;
    unsigned short* L = lt[wid];

    const int gid = blockIdx.x * 4 + wid;
    const int NW  = (N_NODES / 16) * 2;
    if (gid >= NW) return;
    const int ntile = gid >> 1;
    const int part  = gid & 1;
    unsigned short* Tout = part ? Tsrc : Tdst;

    const float* hrow = H + (size_t)(ntile * 16 + n16) * D;
    float4 q0 = *(const float4*)(hrow + kc);
    float4 q1 = *(const float4*)(hrow + kc + 4);
    float4 q2 = *(const float4*)(hrow + 32 + kc);
    float4 q3 = *(const float4*)(hrow + 32 + kc + 4);
    Frag a0, a1;
    a0.u[0] = pk_bf16(q0.x, q0.y); a0.u[1] = pk_bf16(q0.z, q0.w);
    a0.u[2] = pk_bf16(q1.x, q1.y); a0.u[3] = pk_bf16(q1.z, q1.w);
    a1.u[0] = pk_bf16(q2.x, q2.y); a1.u[1] = pk_bf16(q2.z, q2.w);
    a1.u[2] = pk_bf16(q3.x, q3.y); a1.u[3] = pk_bf16(q3.z, q3.w);

    if (part == 0) {
        float4* hp = (float4*)(hinit + (size_t)(ntile * 16 + n16) * D);
        hp[quad * 2]     = q0;
        hp[quad * 2 + 1] = q1;
        hp[8 + quad * 2] = q2;
        hp[9 + quad * 2] = q3;
    }

#pragma unroll
    for (int cbi = 0; cbi < 8; ++cbi) {
        const int col   = cbi * 16 + n16;
        const int sflag = col & 1;
        const int j     = col >> 1;

        Frag b0, b1;
        {
            const uint4* bp = Wpk + ((size_t)(part * 512 + cbi * 64 + lane)) * 2;
            *(uint4*)&b0 = bp[0];
            *(uint4*)&b1 = bp[1];
        }
        float bias = 0.0f;
        if (part == 0) bias = sflag ? bs[j] : bf[j];

        floatx4 acc = {bias, bias, bias, bias};
        acc = __builtin_amdgcn_mfma_f32_16x16x32_bf16(a0.s, b0.s, acc, 0, 0, 0);
        acc = __builtin_amdgcn_mfma_f32_16x16x32_bf16(a1.s, b1.s, acc, 0, 0, 0);

#pragma unroll
        for (int r = 0; r < 4; ++r)
            L[(quad * 4 + r) * NSTR + col] = bf16_1(acc[r]);
    }

#pragma unroll
    for (int it = 0; it < 4; ++it) {
        const int node_l = it * 4 + quad;
        const int c8     = n16 * 8;
        uint4 v = *(const uint4*)(L + node_l * NSTR + c8);
        *(uint4*)(Tout + (size_t)(ntile * 16 + node_l) * 128 + c8) = v;
    }
}

// ---- edge kernel: 2x64 consecutive edges/wave, dbuf gathers, hoisted dst --
__global__ __launch_bounds__(256) void edge_message_mfma(
    const unsigned short* __restrict__ Tdst,  // [N_NODES][128] bf16
    const unsigned short* __restrict__ Tsrc,  // [N_NODES][128] bf16
    const unsigned short* __restrict__ eaS,   // [N_EDGES][32] bf16, sorted
    const int2* __restrict__ sd_sorted,       // [N_EDGES] (src,dst) sorted
    const uint4* __restrict__ WpkE,           // this layer's edge fragments
    float* __restrict__ hout)                 // [N_NODES][64], pre-init = hin
{
    const int lane = threadIdx.x & 63;
    const int wid  = threadIdx.x >> 6;
    const int n16  = lane & 15;
    const int quad = lane >> 4;
    const int c0   = quad * 8;

    Frag bfr[4], bsr[4];
#pragma unroll
    for (int jb = 0; jb < 4; ++jb) {
        *(uint4*)&bfr[jb] = WpkE[((size_t)(jb * 64 + lane)) * 2 + 0];
        *(uint4*)&bsr[jb] = WpkE[((size_t)(jb * 64 + lane)) * 2 + 1];
    }

    // bijective XCD swizzle (nwg = 1563, q = 195, rr = 3)
    const int nwg = gridDim.x;
    const int xcd = blockIdx.x & 7;
    const int idx = blockIdx.x >> 3;
    const int q   = nwg >> 3, rr = nwg & 7;
    const int sb  = (xcd < rr ? xcd * (q + 1) : rr * (q + 1) + (xcd - rr) * q) + idx;
    const int w   = sb * 4 + wid;            // wave slot 0..6251
    if (w >= 6250) return;
    const int base0 = w * 128;               // 128 consecutive edges

    const floatx4 zero = {0.0f, 0.0f, 0.0f, 0.0f};

    // per-quad run-length state: persists across both 64-edge groups
    int cur_d = -1;
    float dfl0 = 0.f, dfl1 = 0.f, dfl2 = 0.f, dfl3 = 0.f;   // dst f-part
    float dfh0 = 0.f, dfh1 = 0.f, dfh2 = 0.f, dfh3 = 0.f;   // dst s-part
    float acc0 = 0.f, acc1 = 0.f, acc2 = 0.f, acc3 = 0.f;

#pragma unroll 1
    for (int g = 0; g < 2; ++g) {
        const int base = base0 + g * 64;

        // this group's 16 sd (quad-uniform, 8x int4)
        const int4* sdp4 = (const int4*)(sd_sorted + base + quad * 16);
        int4 sdq[8];
#pragma unroll
        for (int i = 0; i < 8; ++i) sdq[i] = sdp4[i];

#define SV(e) ((((e) & 1) != 0) ? sdq[(e) >> 1].z : sdq[(e) >> 1].x)
#define DV(e) ((((e) & 1) != 0) ? sdq[(e) >> 1].w : sdq[(e) >> 1].y)

        const unsigned short* aptr =
            eaS + (size_t)(base + (n16 >> 2) * 16 + (n16 & 3)) * 32 + c0;
        Frag af;
        af.s = *(const short8*)aptr;

        // src-row double buffer: [buf][r][jb], static indices after unroll
        unsigned sbuf[2][4][4];
#pragma unroll
        for (int r = 0; r < 4; ++r) {
            const unsigned* srow = (const unsigned*)(Tsrc + (size_t)SV(r) * 128);
            sbuf[0][r][0] = srow[n16];
            sbuf[0][r][1] = srow[16 + n16];
            sbuf[0][r][2] = srow[32 + n16];
            sbuf[0][r][3] = srow[48 + n16];
        }

#pragma unroll
        for (int tt = 0; tt < 4; ++tt) {
            const int cb = tt & 1, nb = cb ^ 1;
            if (tt < 3) {
#pragma unroll
                for (int r = 0; r < 4; ++r) {
                    const unsigned* srow =
                        (const unsigned*)(Tsrc + (size_t)SV(4 * (tt + 1) + r) * 128);
                    sbuf[nb][r][0] = srow[n16];
                    sbuf[nb][r][1] = srow[16 + n16];
                    sbuf[nb][r][2] = srow[32 + n16];
                    sbuf[nb][r][3] = srow[48 + n16];
                }
            }

            floatx4 accf[4], accs[4];
#pragma unroll
            for (int jb = 0; jb < 4; ++jb) {
                accf[jb] = __builtin_amdgcn_mfma_f32_16x16x32_bf16(af.s, bfr[jb].s, zero, 0, 0, 0);
                accs[jb] = __builtin_amdgcn_mfma_f32_16x16x32_bf16(af.s, bsr[jb].s, zero, 0, 0, 0);
            }
            if (tt < 3) af.s = *(const short8*)(aptr + (tt + 1) * 128);

#pragma unroll
            for (int r = 0; r < 4; ++r) {
                const int dv = DV(4 * tt + r);
                if (dv != cur_d) {
                    if (cur_d >= 0) {
                        float* hp = hout + (size_t)cur_d * D + n16;
                        atomicAdd(hp +  0, acc0);  // 16 lanes contiguous 64B
                        atomicAdd(hp + 16, acc1);
                        atomicAdd(hp + 32, acc2);
                        atomicAdd(hp + 48, acc3);
                    }
                    cur_d = dv;
                    const unsigned* drow = (const unsigned*)(Tdst + (size_t)dv * 128);
                    unsigned t0 = drow[n16];
                    unsigned t1 = drow[16 + n16];
                    unsigned t2 = drow[32 + n16];
                    unsigned t3 = drow[48 + n16];
                    dfl0 = upk(t0 & 0xFFFFu); dfh0 = upk(t0 >> 16);
                    dfl1 = upk(t1 & 0xFFFFu); dfh1 = upk(t1 >> 16);
                    dfl2 = upk(t2 & 0xFFFFu); dfh2 = upk(t2 >> 16);
                    dfl3 = upk(t3 & 0xFFFFu); dfh3 = upk(t3 >> 16);
                    acc0 = acc1 = acc2 = acc3 = 0.f;
                }
#pragma unroll
                for (int jb = 0; jb < 4; ++jb) {
                    float dl = (jb == 0) ? dfl0 : (jb == 1) ? dfl1 : (jb == 2) ? dfl2 : dfl3;
                    float dh = (jb == 0) ? dfh0 : (jb == 1) ? dfh1 : (jb == 2) ? dfh2 : dfh3;
                    unsigned sv = sbuf[cb][r][jb];
                    float vf = accf[jb][r] + dl + upk(sv & 0xFFFFu);
                    float vs = accs[jb][r] + dh + upk(sv >> 16);
                    float sig = __builtin_amdgcn_rcpf(1.0f + __expf(-vf));
                    float spl = fmaxf(vs, 0.0f) + __logf(1.0f + __expf(-fabsf(vs)));
                    float msg = sig * spl;
                    if      (jb == 0) acc0 += msg;
                    else if (jb == 1) acc1 += msg;
                    else if (jb == 2) acc2 += msg;
                    else              acc3 += msg;
                }
            }
        }
#undef SV
#undef DV
    }
    // final flush (cur_d always valid here)
    {
        float* hp = hout + (size_t)cur_d * D + n16;
        atomicAdd(hp +  0, acc0);
        atomicAdd(hp + 16, acc1);
        atomicAdd(hp + 32, acc2);
        atomicAdd(hp + 48, acc3);
    }
}

// segment_sum(h, batch) into pooled[N_GRAPHS][64]
__global__ __launch_bounds__(256) void pool_kernel(
    const float* __restrict__ h,
    const int* __restrict__ batch,
    float* __restrict__ pooled)
{
    const int lane = threadIdx.x & 63;
    const int wid  = threadIdx.x >> 6;
    const int w = blockIdx.x * 4 + wid;
    const int n0 = w * 16;
    if (n0 >= N_NODES) return;
    const int nend = (n0 + 16 < N_NODES) ? (n0 + 16) : N_NODES;

    int cur = batch[n0];
    float acc = 0.0f;
    for (int n = n0; n < nend; ++n) {
        int b = batch[n];                      // wave-uniform scalar load
        float v = h[(size_t)n * D + lane];
        if (b != cur) {
            atomicAdd(&pooled[(size_t)cur * D + lane], acc);
            cur = b; acc = v;
        } else {
            acc += v;
        }
    }
    atomicAdd(&pooled[(size_t)cur * D + lane], acc);
}

__global__ __launch_bounds__(256) void out_kernel(
    const float* __restrict__ pooled,
    const float* __restrict__ Wout,
    const float* __restrict__ bout,
    float* __restrict__ out)
{
    const int g = blockIdx.x * blockDim.x + threadIdx.x;
    if (g >= N_GRAPHS) return;
    float acc = bout[0];
#pragma unroll
    for (int j = 0; j < D; ++j) acc = fmaf(pooled[(size_t)g * D + j], Wout[j], acc);
    out[g] = acc;
}

extern "C" void kernel_launch(void* const* d_in, const int* in_sizes, int n_in,
                              void* d_out, int out_size, void* d_ws, size_t ws_size,
                              hipStream_t stream) {
    const float* x     = (const float*)d_in[0];
    const int*   ei    = (const int*)  d_in[1];
    const float* ea    = (const float*)d_in[2];
    const int*   batch = (const int*)  d_in[3];
    const float* Wf1   = (const float*)d_in[4];
    const float* bf1   = (const float*)d_in[5];
    const float* Ws1   = (const float*)d_in[6];
    const float* bs1   = (const float*)d_in[7];
    const float* Wf2   = (const float*)d_in[8];
    const float* bf2   = (const float*)d_in[9];
    const float* Ws2   = (const float*)d_in[10];
    const float* bs2   = (const float*)d_in[11];
    const float* Wout  = (const float*)d_in[12];
    const float* bout  = (const float*)d_in[13];
    float* out = (float*)d_out;

    // workspace carve (~113 MB)
    char* base = (char*)d_ws;
    size_t o = 0;
    unsigned short* Tdst = (unsigned short*)(base + o); o += (size_t)N_NODES * 128 * 2;
    unsigned short* Tsrc = (unsigned short*)(base + o); o += (size_t)N_NODES * 128 * 2;
    unsigned short* eaS  = (unsigned short*)(base + o); o += (size_t)N_EDGES * 32 * 2;
    float* h1     = (float*)(base + o); o += (size_t)N_NODES * D * 4;
    float* h2     = (float*)(base + o); o += (size_t)N_NODES * D * 4;
    float* pooled = (float*)(base + o); o += (size_t)N_GRAPHS * D * 4;
    int* deg  = (int*)(base + o); o += (size_t)N_NODES * 4;
    int* off  = (int*)(base + o); o += (size_t)(N_NODES + 1) * 4;
    int* tsum = (int*)(base + o); o += 256 * 4;
    int2* sd_sorted = (int2*)(base + o); o += (size_t)N_EDGES * 8;
    int* rank = (int*)(base + o); o += (size_t)N_EDGES * 4;
    uint4* WpkNT = (uint4*)(base + o); o += (size_t)2 * 1024 * 2 * 16;
    uint4* WpkE  = (uint4*)(base + o); o += (size_t)2 * 256 * 2 * 16;

    // 1. pack_W + zero(deg) + zero(pooled)
    setup_kernel<<<334, 256, 0, stream>>>(Wf1, Ws1, Wf2, Ws2,
                                          WpkNT, WpkE, deg, pooled);
    // 2. hist (+rank)
    hist_kernel<<<NB_SCAT, 256, 0, stream>>>(ei, deg, rank);
    // 3-4. scan
    scan1<<<NB_SCAN, 256, 0, stream>>>(deg, off, tsum);
    scan23<<<NB_SCAN, 256, 0, stream>>>(off, tsum);
    // 5. fused scatter_pack + node_transform L1 (writes h1 = x)
    fused_scatter_nt<<<NB_FUSED, 256, 0, stream>>>(
        ei, off, rank, ea, eaS, sd_sorted,
        x, bf1, bs1, WpkNT, Tdst, Tsrc, h1);
    // 6. layer 1 edge (flush -> h1)
    edge_message_mfma<<<NB_EDGE, 256, 0, stream>>>(Tdst, Tsrc, eaS, sd_sorted,
                                                   WpkE, h1);
    // 7. layer 2 node transform (writes h2 = h1)
    node_transform_mfma<<<1563, 256, 0, stream>>>(h1, bf2, bs2, WpkNT + 2048,
                                                  Tdst, Tsrc, h2);
    // 8. layer 2 edge (flush -> h2)
    edge_message_mfma<<<NB_EDGE, 256, 0, stream>>>(Tdst, Tsrc, eaS, sd_sorted,
                                                   WpkE + 512, h2);
    // 9. pool + 10. out
    pool_kernel<<<782, 256, 0, stream>>>(h2, batch, pooled);
    out_kernel<<<2, 256, 0, stream>>>(pooled, Wout, bout, out);
}

// Round 13
// 449.040 us; speedup vs baseline: 1.2216x; 1.2216x over previous
//
#include <hip/hip_runtime.h>
#include <math.h>

#define N_NODES 50000
#define N_EDGES 800000
#define N_GRAPHS 512
#define D 64
#define DE 32
#define NB_SCAN 196            // ceil(50000/256)
#define NSTR 136               // NT LDS row stride (ushorts), 272B = 16B-aligned
#define NB_SCAT 3125           // scatter blocks (800K/256)
#define NB_FUSED 4689          // 3 * 1563: role = blockIdx % 3 (2 -> NT)
#define NB_EDGE 1563           // edge blocks: 6250 waves x 128 edges

// ---------------------------------------------------------------------------
// R21: single-variable revert of R20's proven-bad change. R20's
// __builtin_nontemporal_store on scatter's random writes DOUBLED fused
// (91->182us, WRITE 120->182MB): NT bypasses L2 write-combining, so each
// 16B store became its own partial-line HBM transaction. Sorted edges
// sharing a dst put adjacent pos rows on shared lines — the L2 merged
// those for free. LAW refined: NT stores only for full-line streaming;
// random sub-line writes NEED L2 write-combining. Plain stores restored.
// Kept from R20 (now cleanly measurable): hoisted dst unpack (8 upk/edge ->
// 8 upk/run), 2x64 consecutive edges/wave (state persists, W-frags
// amortized).
// R17 lesson: atomics need line-SPREAD (h1/h2 50K rows, never pooled's 512).
// R14 atomic law: flush = 4 atomics x 16 lanes contiguous 64B = 1 line/inst.
// R19 lesson: permutation cost is conserved; pay it on the side touched
// fewest times (write side, once).
//
// MFMA 16x16x32 bf16 fragment maps (m89/m120-verified):
//   A[m][k]: m = lane&15, k = (lane>>4)*8 + i
//   B[k][n]: n = lane&15, k = (lane>>4)*8 + i
//   C/D    : col n = lane&15, row m = (lane>>4)*4 + reg
// Edge A-row permutation: row m of MFMA tt <- edge base + 16*(m>>2)+(m&3)+4tt
//   => quad q processes edges base+16q .. base+16q+15 IN ORDER.
// Edge column map: j = 16*jb + n16 (contiguous-flush).
// ---------------------------------------------------------------------------

typedef __attribute__((ext_vector_type(8))) short short8;
typedef __attribute__((ext_vector_type(4))) float floatx4;
union Frag { short8 s; unsigned u[4]; };
union U4   { uint4 v; unsigned u[4]; };

__device__ inline unsigned pk_bf16(float lo, float hi) {
    unsigned a = __float_as_uint(lo);
    unsigned b = __float_as_uint(hi);
    a = (a + 0x7FFFu + ((a >> 16) & 1u)) >> 16;
    b = (b + 0x7FFFu + ((b >> 16) & 1u)) >> 16;
    return a | (b << 16);
}
__device__ inline unsigned short bf16_1(float v) {
    unsigned a = __float_as_uint(v);
    return (unsigned short)((a + 0x7FFFu + ((a >> 16) & 1u)) >> 16);
}
__device__ inline float upk(unsigned u16) { return __uint_as_float(u16 << 16); }

// ---- setup: pack_W (blocks 0..9) + zero deg (10..205) + zero pooled -------
__global__ __launch_bounds__(256) void setup_kernel(
    const float* __restrict__ Wf1, const float* __restrict__ Ws1,
    const float* __restrict__ Wf2, const float* __restrict__ Ws2,
    uint4* __restrict__ WpkNT, uint4* __restrict__ WpkE,
    int* __restrict__ deg, float* __restrict__ pooled)
{
    const int b = blockIdx.x;
    if (b >= 206) {                       // zero pooled: 128 blocks
        int i = (b - 206) * 256 + threadIdx.x;
        if (i < N_GRAPHS * D) pooled[i] = 0.0f;
        return;
    }
    if (b >= 10) {                        // zero deg: 196 blocks
        int i = (b - 10) * 256 + threadIdx.x;
        if (i < N_NODES) deg[i] = 0;
        return;
    }
    const int layer = b / 5;
    const float* Wf = layer ? Wf2 : Wf1;
    const float* Ws = layer ? Ws2 : Ws1;
    const int i = (b % 5) * 256 + threadIdx.x;   // 0..1279
    if (i < 1024) {
        const int p    = i >> 9;
        const int cbi  = (i >> 6) & 7;
        const int l    = i & 63;
        const int n16  = l & 15, quad = l >> 4, kc = quad * 8;
        const int col  = cbi * 16 + n16;
        const int j    = col >> 1;
        const float* Wsel = (col & 1) ? Ws : Wf;
        const int rbase = p * 64;
        U4 b0, b1;
#pragma unroll
        for (int pp = 0; pp < 4; ++pp) {
            b0.u[pp] = pk_bf16(Wsel[(rbase + kc + 2 * pp) * 64 + j],
                               Wsel[(rbase + kc + 2 * pp + 1) * 64 + j]);
            b1.u[pp] = pk_bf16(Wsel[(rbase + 32 + kc + 2 * pp) * 64 + j],
                               Wsel[(rbase + 32 + kc + 2 * pp + 1) * 64 + j]);
        }
        uint4* o = WpkNT + ((size_t)layer * 1024 + i) * 2;
        o[0] = b0.v; o[1] = b1.v;
    } else if (i < 1280) {
        const int k  = i - 1024;
        const int jb = k >> 6;
        const int l  = k & 63;
        const int n16 = l & 15, quad = l >> 4, c0 = quad * 8;
        const int j = jb * 16 + n16;             // contiguous-flush map
        U4 bf_, bs_;
#pragma unroll
        for (int pp = 0; pp < 4; ++pp) {
            bf_.u[pp] = pk_bf16(Wf[(128 + c0 + 2 * pp) * 64 + j],
                                Wf[(128 + c0 + 2 * pp + 1) * 64 + j]);
            bs_.u[pp] = pk_bf16(Ws[(128 + c0 + 2 * pp) * 64 + j],
                                Ws[(128 + c0 + 2 * pp + 1) * 64 + j]);
        }
        uint4* o = WpkE + ((size_t)layer * 256 + k) * 2;
        o[0] = bf_.v; o[1] = bs_.v;
    }
}

// ---- hist (+rank): scatter needs no atomic of its own ----------------------
__global__ __launch_bounds__(256) void hist_kernel(
    const int* __restrict__ ei, int* __restrict__ deg, int* __restrict__ rank)
{
    int e = blockIdx.x * 256 + threadIdx.x;
    rank[e] = atomicAdd(&deg[ei[N_EDGES + e]], 1);
}

__global__ __launch_bounds__(256) void scan1(
    const int* __restrict__ deg, int* __restrict__ off, int* __restrict__ tsum)
{
    __shared__ int s[256];
    int i = blockIdx.x * 256 + threadIdx.x;
    s[threadIdx.x] = (i < N_NODES) ? deg[i] : 0;
    __syncthreads();
    if (threadIdx.x == 0) {
        int run = 0;
        for (int k = 0; k < 256; ++k) { int t = s[k]; s[k] = run; run += t; }
        tsum[blockIdx.x] = run;
    }
    __syncthreads();
    if (i < N_NODES) off[i] = s[threadIdx.x];
}

// scan2+scan3 fused: every block redundantly computes its exclusive prefix
__global__ __launch_bounds__(256) void scan23(
    int* __restrict__ off, const int* __restrict__ tsum)
{
    __shared__ int pfx;
    if (threadIdx.x == 0) {
        int run = 0;
        for (int k = 0; k < (int)blockIdx.x; ++k) run += tsum[k];
        pfx = run;
    }
    __syncthreads();
    int i = blockIdx.x * 256 + threadIdx.x;
    if (i < N_NODES) off[i] += pfx;
    if (i == N_NODES) off[i] = N_EDGES;
}

// ---- FUSED: scatter_pack + node_transform L1, roles INTERLEAVED -----------
// blockIdx % 3 == 2 -> NT (1563 blocks); else scatter (3126 slots, 3125 used)
__global__ __launch_bounds__(256) void fused_scatter_nt(
    const int* __restrict__ ei, const int* __restrict__ off,
    const int* __restrict__ rank, const float* __restrict__ ea,
    unsigned short* __restrict__ eaS, int2* __restrict__ sd_sorted,
    const float* __restrict__ H,
    const float* __restrict__ bf, const float* __restrict__ bs,
    const uint4* __restrict__ Wpk,
    unsigned short* __restrict__ Tdst, unsigned short* __restrict__ Tsrc,
    float* __restrict__ hinit)
{
    __shared__ unsigned short lt[4][16 * NSTR];
    const int k = blockIdx.x;

    if ((k % 3) != 2) {
        const int sid = k - (k / 3);
        if (sid >= NB_SCAT) return;
        int e = sid * 256 + threadIdx.x;
        int s = ei[e];
        int d = ei[N_EDGES + e];
        int pos = off[d] + rank[e];
        sd_sorted[pos] = make_int2(s, d);    // plain store: L2 write-combining

        const float4* src4 = (const float4*)(ea + (size_t)e * 32);
        uint4* dst16 = (uint4*)(eaS + (size_t)pos * 32);
#pragma unroll
        for (int q = 0; q < 2; ++q) {
            float4 v0 = src4[4 * q + 0];
            float4 v1 = src4[4 * q + 1];
            float4 v2 = src4[4 * q + 2];
            float4 v3 = src4[4 * q + 3];
            uint4 o0;
            o0.x = pk_bf16(v0.x, v0.y); o0.y = pk_bf16(v0.z, v0.w);
            o0.z = pk_bf16(v1.x, v1.y); o0.w = pk_bf16(v1.z, v1.w);
            uint4 o1;
            o1.x = pk_bf16(v2.x, v2.y); o1.y = pk_bf16(v2.z, v2.w);
            o1.z = pk_bf16(v3.x, v3.y); o1.w = pk_bf16(v3.z, v3.w);
            dst16[2 * q + 0] = o0;
            dst16[2 * q + 1] = o1;
        }
        return;
    }

    const int lane = threadIdx.x & 63;
    const int wid  = threadIdx.x >> 6;
    const int n16  = lane & 15;
    const int quad = lane >> 4;
    const int kc   = quad * 8;
    unsigned short* L = lt[wid];

    const int gid = (k / 3) * 4 + wid;
    const int NW  = (N_NODES / 16) * 2;
    if (gid >= NW) return;
    const int ntile = gid >> 1;
    const int part  = gid & 1;
    unsigned short* Tout = part ? Tsrc : Tdst;

    const float* hrow = H + (size_t)(ntile * 16 + n16) * D;
    float4 q0 = *(const float4*)(hrow + kc);
    float4 q1 = *(const float4*)(hrow + kc + 4);
    float4 q2 = *(const float4*)(hrow + 32 + kc);
    float4 q3 = *(const float4*)(hrow + 32 + kc + 4);
    Frag a0, a1;
    a0.u[0] = pk_bf16(q0.x, q0.y); a0.u[1] = pk_bf16(q0.z, q0.w);
    a0.u[2] = pk_bf16(q1.x, q1.y); a0.u[3] = pk_bf16(q1.z, q1.w);
    a1.u[0] = pk_bf16(q2.x, q2.y); a1.u[1] = pk_bf16(q2.z, q2.w);
    a1.u[2] = pk_bf16(q3.x, q3.y); a1.u[3] = pk_bf16(q3.z, q3.w);

    if (part == 0) {
        float4* hp = (float4*)(hinit + (size_t)(ntile * 16 + n16) * D);
        hp[quad * 2]     = q0;
        hp[quad * 2 + 1] = q1;
        hp[8 + quad * 2] = q2;
        hp[9 + quad * 2] = q3;
    }

#pragma unroll
    for (int cbi = 0; cbi < 8; ++cbi) {
        const int col   = cbi * 16 + n16;
        const int sflag = col & 1;
        const int j     = col >> 1;

        Frag b0, b1;
        {
            const uint4* bp = Wpk + ((size_t)(part * 512 + cbi * 64 + lane)) * 2;
            *(uint4*)&b0 = bp[0];
            *(uint4*)&b1 = bp[1];
        }
        float bias = 0.0f;
        if (part == 0) bias = sflag ? bs[j] : bf[j];

        floatx4 acc = {bias, bias, bias, bias};
        acc = __builtin_amdgcn_mfma_f32_16x16x32_bf16(a0.s, b0.s, acc, 0, 0, 0);
        acc = __builtin_amdgcn_mfma_f32_16x16x32_bf16(a1.s, b1.s, acc, 0, 0, 0);

#pragma unroll
        for (int r = 0; r < 4; ++r)
            L[(quad * 4 + r) * NSTR + col] = bf16_1(acc[r]);
    }

#pragma unroll
    for (int it = 0; it < 4; ++it) {
        const int node_l = it * 4 + quad;
        const int c8     = n16 * 8;
        uint4 v = *(const uint4*)(L + node_l * NSTR + c8);
        *(uint4*)(Tout + (size_t)(ntile * 16 + node_l) * 128 + c8) = v;
    }
}

// ---- node transform (standalone, layer 2) ---------------------------------
__global__ __launch_bounds__(256) void node_transform_mfma(
    const float* __restrict__ H,
    const float* __restrict__ bf,
    const float* __restrict__ bs,
    const uint4* __restrict__ Wpk,
    unsigned short* __restrict__ Tdst,
    unsigned short* __restrict__ Tsrc,
    float* __restrict__ hinit)
{
    __shared__ unsigned short lt[4][16 * NSTR];
    const int lane = threadIdx.x & 63;
    const int wid  = threadIdx.x >> 6;
    const int n16  = lane & 15;
    const int quad = lane >> 4;
    const int kc   = quad * 8;
    unsigned short* L = lt[wid];

    const int gid = blockIdx.x * 4 + wid;
    const int NW  = (N_NODES / 16) * 2;
    if (gid >= NW) return;
    const int ntile = gid >> 1;
    const int part  = gid & 1;
    unsigned short* Tout = part ? Tsrc : Tdst;

    const float* hrow = H + (size_t)(ntile * 16 + n16) * D;
    float4 q0 = *(const float4*)(hrow + kc);
    float4 q1 = *(const float4*)(hrow + kc + 4);
    float4 q2 = *(const float4*)(hrow + 32 + kc);
    float4 q3 = *(const float4*)(hrow + 32 + kc + 4);
    Frag a0, a1;
    a0.u[0] = pk_bf16(q0.x, q0.y); a0.u[1] = pk_bf16(q0.z, q0.w);
    a0.u[2] = pk_bf16(q1.x, q1.y); a0.u[3] = pk_bf16(q1.z, q1.w);
    a1.u[0] = pk_bf16(q2.x, q2.y); a1.u[1] = pk_bf16(q2.z, q2.w);
    a1.u[2] = pk_bf16(q3.x, q3.y); a1.u[3] = pk_bf16(q3.z, q3.w);

    if (part == 0) {
        float4* hp = (float4*)(hinit + (size_t)(ntile * 16 + n16) * D);
        hp[quad * 2]     = q0;
        hp[quad * 2 + 1] = q1;
        hp[8 + quad * 2] = q2;
        hp[9 + quad * 2] = q3;
    }

#pragma unroll
    for (int cbi = 0; cbi < 8; ++cbi) {
        const int col   = cbi * 16 + n16;
        const int sflag = col & 1;
        const int j     = col >> 1;

        Frag b0, b1;
        {
            const uint4* bp = Wpk + ((size_t)(part * 512 + cbi * 64 + lane)) * 2;
            *(uint4*)&b0 = bp[0];
            *(uint4*)&b1 = bp[1];
        }
        float bias = 0.0f;
        if (part == 0) bias = sflag ? bs[j] : bf[j];

        floatx4 acc = {bias, bias, bias, bias};
        acc = __builtin_amdgcn_mfma_f32_16x16x32_bf16(a0.s, b0.s, acc, 0, 0, 0);
        acc = __builtin_amdgcn_mfma_f32_16x16x32_bf16(a1.s, b1.s, acc, 0, 0, 0);

#pragma unroll
        for (int r = 0; r < 4; ++r)
            L[(quad * 4 + r) * NSTR + col] = bf16_1(acc[r]);
    }

#pragma unroll
    for (int it = 0; it < 4; ++it) {
        const int node_l = it * 4 + quad;
        const int c8     = n16 * 8;
        uint4 v = *(const uint4*)(L + node_l * NSTR + c8);
        *(uint4*)(Tout + (size_t)(ntile * 16 + node_l) * 128 + c8) = v;
    }
}

// ---- edge kernel: 2x64 consecutive edges/wave, dbuf gathers, hoisted dst --
__global__ __launch_bounds__(256) void edge_message_mfma(
    const unsigned short* __restrict__ Tdst,  // [N_NODES][128] bf16
    const unsigned short* __restrict__ Tsrc,  // [N_NODES][128] bf16
    const unsigned short* __restrict__ eaS,   // [N_EDGES][32] bf16, sorted
    const int2* __restrict__ sd_sorted,       // [N_EDGES] (src,dst) sorted
    const uint4* __restrict__ WpkE,           // this layer's edge fragments
    float* __restrict__ hout)                 // [N_NODES][64], pre-init = hin
{
    const int lane = threadIdx.x & 63;
    const int wid  = threadIdx.x >> 6;
    const int n16  = lane & 15;
    const int quad = lane >> 4;
    const int c0   = quad * 8;

    Frag bfr[4], bsr[4];
#pragma unroll
    for (int jb = 0; jb < 4; ++jb) {
        *(uint4*)&bfr[jb] = WpkE[((size_t)(jb * 64 + lane)) * 2 + 0];
        *(uint4*)&bsr[jb] = WpkE[((size_t)(jb * 64 + lane)) * 2 + 1];
    }

    // bijective XCD swizzle (nwg = 1563, q = 195, rr = 3)
    const int nwg = gridDim.x;
    const int xcd = blockIdx.x & 7;
    const int idx = blockIdx.x >> 3;
    const int q   = nwg >> 3, rr = nwg & 7;
    const int sb  = (xcd < rr ? xcd * (q + 1) : rr * (q + 1) + (xcd - rr) * q) + idx;
    const int w   = sb * 4 + wid;            // wave slot 0..6251
    if (w >= 6250) return;
    const int base0 = w * 128;               // 128 consecutive edges

    const floatx4 zero = {0.0f, 0.0f, 0.0f, 0.0f};

    // per-quad run-length state: persists across both 64-edge groups
    int cur_d = -1;
    float dfl0 = 0.f, dfl1 = 0.f, dfl2 = 0.f, dfl3 = 0.f;   // dst f-part
    float dfh0 = 0.f, dfh1 = 0.f, dfh2 = 0.f, dfh3 = 0.f;   // dst s-part
    float acc0 = 0.f, acc1 = 0.f, acc2 = 0.f, acc3 = 0.f;

#pragma unroll 1
    for (int g = 0; g < 2; ++g) {
        const int base = base0 + g * 64;

        // this group's 16 sd (quad-uniform, 8x int4)
        const int4* sdp4 = (const int4*)(sd_sorted + base + quad * 16);
        int4 sdq[8];
#pragma unroll
        for (int i = 0; i < 8; ++i) sdq[i] = sdp4[i];

#define SV(e) ((((e) & 1) != 0) ? sdq[(e) >> 1].z : sdq[(e) >> 1].x)
#define DV(e) ((((e) & 1) != 0) ? sdq[(e) >> 1].w : sdq[(e) >> 1].y)

        const unsigned short* aptr =
            eaS + (size_t)(base + (n16 >> 2) * 16 + (n16 & 3)) * 32 + c0;
        Frag af;
        af.s = *(const short8*)aptr;

        // src-row double buffer: [buf][r][jb], static indices after unroll
        unsigned sbuf[2][4][4];
#pragma unroll
        for (int r = 0; r < 4; ++r) {
            const unsigned* srow = (const unsigned*)(Tsrc + (size_t)SV(r) * 128);
            sbuf[0][r][0] = srow[n16];
            sbuf[0][r][1] = srow[16 + n16];
            sbuf[0][r][2] = srow[32 + n16];
            sbuf[0][r][3] = srow[48 + n16];
        }

#pragma unroll
        for (int tt = 0; tt < 4; ++tt) {
            const int cb = tt & 1, nb = cb ^ 1;
            if (tt < 3) {
#pragma unroll
                for (int r = 0; r < 4; ++r) {
                    const unsigned* srow =
                        (const unsigned*)(Tsrc + (size_t)SV(4 * (tt + 1) + r) * 128);
                    sbuf[nb][r][0] = srow[n16];
                    sbuf[nb][r][1] = srow[16 + n16];
                    sbuf[nb][r][2] = srow[32 + n16];
                    sbuf[nb][r][3] = srow[48 + n16];
                }
            }

            floatx4 accf[4], accs[4];
#pragma unroll
            for (int jb = 0; jb < 4; ++jb) {
                accf[jb] = __builtin_amdgcn_mfma_f32_16x16x32_bf16(af.s, bfr[jb].s, zero, 0, 0, 0);
                accs[jb] = __builtin_amdgcn_mfma_f32_16x16x32_bf16(af.s, bsr[jb].s, zero, 0, 0, 0);
            }
            if (tt < 3) af.s = *(const short8*)(aptr + (tt + 1) * 128);

#pragma unroll
            for (int r = 0; r < 4; ++r) {
                const int dv = DV(4 * tt + r);
                if (dv != cur_d) {
                    if (cur_d >= 0) {
                        float* hp = hout + (size_t)cur_d * D + n16;
                        atomicAdd(hp +  0, acc0);  // 16 lanes contiguous 64B
                        atomicAdd(hp + 16, acc1);
                        atomicAdd(hp + 32, acc2);
                        atomicAdd(hp + 48, acc3);
                    }
                    cur_d = dv;
                    const unsigned* drow = (const unsigned*)(Tdst + (size_t)dv * 128);
                    unsigned t0 = drow[n16];
                    unsigned t1 = drow[16 + n16];
                    unsigned t2 = drow[32 + n16];
                    unsigned t3 = drow[48 + n16];
                    dfl0 = upk(t0 & 0xFFFFu); dfh0 = upk(t0 >> 16);
                    dfl1 = upk(t1 & 0xFFFFu); dfh1 = upk(t1 >> 16);
                    dfl2 = upk(t2 & 0xFFFFu); dfh2 = upk(t2 >> 16);
                    dfl3 = upk(t3 & 0xFFFFu); dfh3 = upk(t3 >> 16);
                    acc0 = acc1 = acc2 = acc3 = 0.f;
                }
#pragma unroll
                for (int jb = 0; jb < 4; ++jb) {
                    float dl = (jb == 0) ? dfl0 : (jb == 1) ? dfl1 : (jb == 2) ? dfl2 : dfl3;
                    float dh = (jb == 0) ? dfh0 : (jb == 1) ? dfh1 : (jb == 2) ? dfh2 : dfh3;
                    unsigned sv = sbuf[cb][r][jb];
                    float vf = accf[jb][r] + dl + upk(sv & 0xFFFFu);
                    float vs = accs[jb][r] + dh + upk(sv >> 16);
                    float sig = __builtin_amdgcn_rcpf(1.0f + __expf(-vf));
                    float spl = fmaxf(vs, 0.0f) + __logf(1.0f + __expf(-fabsf(vs)));
                    float msg = sig * spl;
                    if      (jb == 0) acc0 += msg;
                    else if (jb == 1) acc1 += msg;
                    else if (jb == 2) acc2 += msg;
                    else              acc3 += msg;
                }
            }
        }
#undef SV
#undef DV
    }
    // final flush (cur_d always valid here)
    {
        float* hp = hout + (size_t)cur_d * D + n16;
        atomicAdd(hp +  0, acc0);
        atomicAdd(hp + 16, acc1);
        atomicAdd(hp + 32, acc2);
        atomicAdd(hp + 48, acc3);
    }
}

// segment_sum(h, batch) into pooled[N_GRAPHS][64]
__global__ __launch_bounds__(256) void pool_kernel(
    const float* __restrict__ h,
    const int* __restrict__ batch,
    float* __restrict__ pooled)
{
    const int lane = threadIdx.x & 63;
    const int wid  = threadIdx.x >> 6;
    const int w = blockIdx.x * 4 + wid;
    const int n0 = w * 16;
    if (n0 >= N_NODES) return;
    const int nend = (n0 + 16 < N_NODES) ? (n0 + 16) : N_NODES;

    int cur = batch[n0];
    float acc = 0.0f;
    for (int n = n0; n < nend; ++n) {
        int b = batch[n];                      // wave-uniform scalar load
        float v = h[(size_t)n * D + lane];
        if (b != cur) {
            atomicAdd(&pooled[(size_t)cur * D + lane], acc);
            cur = b; acc = v;
        } else {
            acc += v;
        }
    }
    atomicAdd(&pooled[(size_t)cur * D + lane], acc);
}

__global__ __launch_bounds__(256) void out_kernel(
    const float* __restrict__ pooled,
    const float* __restrict__ Wout,
    const float* __restrict__ bout,
    float* __restrict__ out)
{
    const int g = blockIdx.x * blockDim.x + threadIdx.x;
    if (g >= N_GRAPHS) return;
    float acc = bout[0];
#pragma unroll
    for (int j = 0; j < D; ++j) acc = fmaf(pooled[(size_t)g * D + j], Wout[j], acc);
    out[g] = acc;
}

extern "C" void kernel_launch(void* const* d_in, const int* in_sizes, int n_in,
                              void* d_out, int out_size, void* d_ws, size_t ws_size,
                              hipStream_t stream) {
    const float* x     = (const float*)d_in[0];
    const int*   ei    = (const int*)  d_in[1];
    const float* ea    = (const float*)d_in[2];
    const int*   batch = (const int*)  d_in[3];
    const float* Wf1   = (const float*)d_in[4];
    const float* bf1   = (const float*)d_in[5];
    const float* Ws1   = (const float*)d_in[6];
    const float* bs1   = (const float*)d_in[7];
    const float* Wf2   = (const float*)d_in[8];
    const float* bf2   = (const float*)d_in[9];
    const float* Ws2   = (const float*)d_in[10];
    const float* bs2   = (const float*)d_in[11];
    const float* Wout  = (const float*)d_in[12];
    const float* bout  = (const float*)d_in[13];
    float* out = (float*)d_out;

    // workspace carve (~113 MB)
    char* base = (char*)d_ws;
    size_t o = 0;
    unsigned short* Tdst = (unsigned short*)(base + o); o += (size_t)N_NODES * 128 * 2;
    unsigned short* Tsrc = (unsigned short*)(base + o); o += (size_t)N_NODES * 128 * 2;
    unsigned short* eaS  = (unsigned short*)(base + o); o += (size_t)N_EDGES * 32 * 2;
    float* h1     = (float*)(base + o); o += (size_t)N_NODES * D * 4;
    float* h2     = (float*)(base + o); o += (size_t)N_NODES * D * 4;
    float* pooled = (float*)(base + o); o += (size_t)N_GRAPHS * D * 4;
    int* deg  = (int*)(base + o); o += (size_t)N_NODES * 4;
    int* off  = (int*)(base + o); o += (size_t)(N_NODES + 1) * 4;
    int* tsum = (int*)(base + o); o += 256 * 4;
    int2* sd_sorted = (int2*)(base + o); o += (size_t)N_EDGES * 8;
    int* rank = (int*)(base + o); o += (size_t)N_EDGES * 4;
    uint4* WpkNT = (uint4*)(base + o); o += (size_t)2 * 1024 * 2 * 16;
    uint4* WpkE  = (uint4*)(base + o); o += (size_t)2 * 256 * 2 * 16;

    // 1. pack_W + zero(deg) + zero(pooled)
    setup_kernel<<<334, 256, 0, stream>>>(Wf1, Ws1, Wf2, Ws2,
                                          WpkNT, WpkE, deg, pooled);
    // 2. hist (+rank)
    hist_kernel<<<NB_SCAT, 256, 0, stream>>>(ei, deg, rank);
    // 3-4. scan
    scan1<<<NB_SCAN, 256, 0, stream>>>(deg, off, tsum);
    scan23<<<NB_SCAN, 256, 0, stream>>>(off, tsum);
    // 5. fused scatter_pack + node_transform L1 (writes h1 = x)
    fused_scatter_nt<<<NB_FUSED, 256, 0, stream>>>(
        ei, off, rank, ea, eaS, sd_sorted,
        x, bf1, bs1, WpkNT, Tdst, Tsrc, h1);
    // 6. layer 1 edge (flush -> h1)
    edge_message_mfma<<<NB_EDGE, 256, 0, stream>>>(Tdst, Tsrc, eaS, sd_sorted,
                                                   WpkE, h1);
    // 7. layer 2 node transform (writes h2 = h1)
    node_transform_mfma<<<1563, 256, 0, stream>>>(h1, bf2, bs2, WpkNT + 2048,
                                                  Tdst, Tsrc, h2);
    // 8. layer 2 edge (flush -> h2)
    edge_message_mfma<<<NB_EDGE, 256, 0, stream>>>(Tdst, Tsrc, eaS, sd_sorted,
                                                   WpkE + 512, h2);
    // 9. pool + 10. out
    pool_kernel<<<782, 256, 0, stream>>>(h2, batch, pooled);
    out_kernel<<<2, 256, 0, stream>>>(pooled, Wout, bout, out);
}

// Round 14
// 439.853 us; speedup vs baseline: 1.2472x; 1.0209x over previous
//
#include <hip/hip_runtime.h>
#include <math.h>

#define N_NODES 50000
#define N_EDGES 800000
#define N_GRAPHS 512
#define D 64
#define DE 32
#define NB_SCAN 196            // ceil(50000/256)
#define NSTR 136               // NT LDS row stride (ushorts), 272B = 16B-aligned
#define NB_SCAT 3125           // scatter blocks (800K/256)
#define NB_FUSED 4689          // 3 * 1563: role = blockIdx % 3 (2 -> NT)

// ---------------------------------------------------------------------------
// R22: budget audit showed ~100us of unaccounted time; the only unmeasured
// structurally-expensive dispatch is hist (800K device-scope atomic RMWs,
// each deg line serializing ~256 RMWs: 16 counters x avg-degree 16). Fix:
// 8-way sub-histogram deg8[8][N], block b atomics into sub b&7 -> ~32
// RMWs/line. Ranks stay consistent: scan23 emits ABSOLUTE off8[s][d] =
// off[d] + sum_{s'<s} deg8[s'][d]; scatter (same edge->block map -> same
// sub) uses pos = off8[sub][d] + r8[e]. Still 1 random 4B read per edge;
// dst runs contiguous (within-run permutation is sum-safe).
// Also: edge kernel reverted to 64 edges/wave (R21's 2x64 cost ~8us of
// latency hiding); dst-unpack hoist kept.
// R21 law: NT stores only for full-line streaming; random sub-line writes
// need L2 write-combining. R17: atomics need line-SPREAD. R14: flush = 4
// atomics x 16 lanes contiguous 64B. R19: permutation cost conserved; pay
// it once on the write side.
//
// MFMA 16x16x32 bf16 fragment maps (m89/m120-verified):
//   A[m][k]: m = lane&15, k = (lane>>4)*8 + i
//   B[k][n]: n = lane&15, k = (lane>>4)*8 + i
//   C/D    : col n = lane&15, row m = (lane>>4)*4 + reg
// Edge A-row permutation: row m of MFMA tt <- edge base + 16*(m>>2)+(m&3)+4tt
//   => quad q processes edges base+16q .. base+16q+15 IN ORDER.
// Edge column map: j = 16*jb + n16 (contiguous-flush).
// ---------------------------------------------------------------------------

typedef __attribute__((ext_vector_type(8))) short short8;
typedef __attribute__((ext_vector_type(4))) float floatx4;
union Frag { short8 s; unsigned u[4]; };
union U4   { uint4 v; unsigned u[4]; };

__device__ inline unsigned pk_bf16(float lo, float hi) {
    unsigned a = __float_as_uint(lo);
    unsigned b = __float_as_uint(hi);
    a = (a + 0x7FFFu + ((a >> 16) & 1u)) >> 16;
    b = (b + 0x7FFFu + ((b >> 16) & 1u)) >> 16;
    return a | (b << 16);
}
__device__ inline unsigned short bf16_1(float v) {
    unsigned a = __float_as_uint(v);
    return (unsigned short)((a + 0x7FFFu + ((a >> 16) & 1u)) >> 16);
}
__device__ inline float upk(unsigned u16) { return __uint_as_float(u16 << 16); }

// ---- setup: pack_W (0..9) + zero deg8 (10..1572) + zero pooled (1573..) ---
__global__ __launch_bounds__(256) void setup_kernel(
    const float* __restrict__ Wf1, const float* __restrict__ Ws1,
    const float* __restrict__ Wf2, const float* __restrict__ Ws2,
    uint4* __restrict__ WpkNT, uint4* __restrict__ WpkE,
    int* __restrict__ deg8, float* __restrict__ pooled)
{
    const int b = blockIdx.x;
    if (b >= 1573) {                      // zero pooled: 128 blocks
        int i = (b - 1573) * 256 + threadIdx.x;
        if (i < N_GRAPHS * D) pooled[i] = 0.0f;
        return;
    }
    if (b >= 10) {                        // zero deg8: 1563 blocks (400K ints)
        int i = (b - 10) * 256 + threadIdx.x;
        if (i < 8 * N_NODES) deg8[i] = 0;
        return;
    }
    const int layer = b / 5;
    const float* Wf = layer ? Wf2 : Wf1;
    const float* Ws = layer ? Ws2 : Ws1;
    const int i = (b % 5) * 256 + threadIdx.x;   // 0..1279
    if (i < 1024) {
        const int p    = i >> 9;
        const int cbi  = (i >> 6) & 7;
        const int l    = i & 63;
        const int n16  = l & 15, quad = l >> 4, kc = quad * 8;
        const int col  = cbi * 16 + n16;
        const int j    = col >> 1;
        const float* Wsel = (col & 1) ? Ws : Wf;
        const int rbase = p * 64;
        U4 b0, b1;
#pragma unroll
        for (int pp = 0; pp < 4; ++pp) {
            b0.u[pp] = pk_bf16(Wsel[(rbase + kc + 2 * pp) * 64 + j],
                               Wsel[(rbase + kc + 2 * pp + 1) * 64 + j]);
            b1.u[pp] = pk_bf16(Wsel[(rbase + 32 + kc + 2 * pp) * 64 + j],
                               Wsel[(rbase + 32 + kc + 2 * pp + 1) * 64 + j]);
        }
        uint4* o = WpkNT + ((size_t)layer * 1024 + i) * 2;
        o[0] = b0.v; o[1] = b1.v;
    } else if (i < 1280) {
        const int k  = i - 1024;
        const int jb = k >> 6;
        const int l  = k & 63;
        const int n16 = l & 15, quad = l >> 4, c0 = quad * 8;
        const int j = jb * 16 + n16;             // contiguous-flush map
        U4 bf_, bs_;
#pragma unroll
        for (int pp = 0; pp < 4; ++pp) {
            bf_.u[pp] = pk_bf16(Wf[(128 + c0 + 2 * pp) * 64 + j],
                                Wf[(128 + c0 + 2 * pp + 1) * 64 + j]);
            bs_.u[pp] = pk_bf16(Ws[(128 + c0 + 2 * pp) * 64 + j],
                                Ws[(128 + c0 + 2 * pp + 1) * 64 + j]);
        }
        uint4* o = WpkE + ((size_t)layer * 256 + k) * 2;
        o[0] = bf_.v; o[1] = bs_.v;
    }
}

// ---- hist: 8-way sub-histogram (block b -> sub b&7), records sub-rank -----
__global__ __launch_bounds__(256) void hist_kernel(
    const int* __restrict__ ei, int* __restrict__ deg8, int* __restrict__ r8)
{
    const int sub = blockIdx.x & 7;
    int e = blockIdx.x * 256 + threadIdx.x;
    r8[e] = atomicAdd(&deg8[sub * N_NODES + ei[N_EDGES + e]], 1);
}

// scan1: total degree per node (sum of 8 subs) -> block-local prefix
__global__ __launch_bounds__(256) void scan1(
    const int* __restrict__ deg8, int* __restrict__ off, int* __restrict__ tsum)
{
    __shared__ int s[256];
    int i = blockIdx.x * 256 + threadIdx.x;
    int tot = 0;
    if (i < N_NODES) {
#pragma unroll
        for (int ss = 0; ss < 8; ++ss) tot += deg8[ss * N_NODES + i];
    }
    s[threadIdx.x] = tot;
    __syncthreads();
    if (threadIdx.x == 0) {
        int run = 0;
        for (int k = 0; k < 256; ++k) { int t = s[k]; s[k] = run; run += t; }
        tsum[blockIdx.x] = run;
    }
    __syncthreads();
    if (i < N_NODES) off[i] = s[threadIdx.x];
}

// scan23: cross-block prefix + absolute per-sub offsets off8[s][i]
__global__ __launch_bounds__(256) void scan23(
    const int* __restrict__ off, const int* __restrict__ tsum,
    const int* __restrict__ deg8, int* __restrict__ off8)
{
    __shared__ int pfx;
    if (threadIdx.x == 0) {
        int run = 0;
        for (int k = 0; k < (int)blockIdx.x; ++k) run += tsum[k];
        pfx = run;
    }
    __syncthreads();
    int i = blockIdx.x * 256 + threadIdx.x;
    if (i < N_NODES) {
        int running = off[i] + pfx;
#pragma unroll
        for (int ss = 0; ss < 8; ++ss) {
            off8[ss * N_NODES + i] = running;
            running += deg8[ss * N_NODES + i];
        }
    }
}

// ---- FUSED: scatter_pack + node_transform L1, roles INTERLEAVED -----------
// blockIdx % 3 == 2 -> NT (1563 blocks); else scatter (3126 slots, 3125 used)
__global__ __launch_bounds__(256) void fused_scatter_nt(
    const int* __restrict__ ei, const int* __restrict__ off8,
    const int* __restrict__ r8, const float* __restrict__ ea,
    unsigned short* __restrict__ eaS, int2* __restrict__ sd_sorted,
    const float* __restrict__ H,
    const float* __restrict__ bf, const float* __restrict__ bs,
    const uint4* __restrict__ Wpk,
    unsigned short* __restrict__ Tdst, unsigned short* __restrict__ Tsrc,
    float* __restrict__ hinit)
{
    __shared__ unsigned short lt[4][16 * NSTR];
    const int k = blockIdx.x;

    if ((k % 3) != 2) {
        const int sid = k - (k / 3);         // 0..3125; enumerates edge blocks
        if (sid >= NB_SCAT) return;
        const int sub = sid & 7;             // SAME map as hist (block b&7)
        int e = sid * 256 + threadIdx.x;
        int s = ei[e];
        int d = ei[N_EDGES + e];
        int pos = off8[sub * N_NODES + d] + r8[e];
        sd_sorted[pos] = make_int2(s, d);    // plain store: L2 write-combining

        const float4* src4 = (const float4*)(ea + (size_t)e * 32);
        uint4* dst16 = (uint4*)(eaS + (size_t)pos * 32);
#pragma unroll
        for (int q = 0; q < 2; ++q) {
            float4 v0 = src4[4 * q + 0];
            float4 v1 = src4[4 * q + 1];
            float4 v2 = src4[4 * q + 2];
            float4 v3 = src4[4 * q + 3];
            uint4 o0;
            o0.x = pk_bf16(v0.x, v0.y); o0.y = pk_bf16(v0.z, v0.w);
            o0.z = pk_bf16(v1.x, v1.y); o0.w = pk_bf16(v1.z, v1.w);
            uint4 o1;
            o1.x = pk_bf16(v2.x, v2.y); o1.y = pk_bf16(v2.z, v2.w);
            o1.z = pk_bf16(v3.x, v3.y); o1.w = pk_bf16(v3.z, v3.w);
            dst16[2 * q + 0] = o0;
            dst16[2 * q + 1] = o1;
        }
        return;
    }

    const int lane = threadIdx.x & 63;
    const int wid  = threadIdx.x >> 6;
    const int n16  = lane & 15;
    const int quad = lane >> 4;
    const int kc   = quad * 8;
    unsigned short* L = lt[wid];

    const int gid = (k / 3) * 4 + wid;
    const int NW  = (N_NODES / 16) * 2;
    if (gid >= NW) return;
    const int ntile = gid >> 1;
    const int part  = gid & 1;
    unsigned short* Tout = part ? Tsrc : Tdst;

    const float* hrow = H + (size_t)(ntile * 16 + n16) * D;
    float4 q0 = *(const float4*)(hrow + kc);
    float4 q1 = *(const float4*)(hrow + kc + 4);
    float4 q2 = *(const float4*)(hrow + 32 + kc);
    float4 q3 = *(const float4*)(hrow + 32 + kc + 4);
    Frag a0, a1;
    a0.u[0] = pk_bf16(q0.x, q0.y); a0.u[1] = pk_bf16(q0.z, q0.w);
    a0.u[2] = pk_bf16(q1.x, q1.y); a0.u[3] = pk_bf16(q1.z, q1.w);
    a1.u[0] = pk_bf16(q2.x, q2.y); a1.u[1] = pk_bf16(q2.z, q2.w);
    a1.u[2] = pk_bf16(q3.x, q3.y); a1.u[3] = pk_bf16(q3.z, q3.w);

    if (part == 0) {
        float4* hp = (float4*)(hinit + (size_t)(ntile * 16 + n16) * D);
        hp[quad * 2]     = q0;
        hp[quad * 2 + 1] = q1;
        hp[8 + quad * 2] = q2;
        hp[9 + quad * 2] = q3;
    }

#pragma unroll
    for (int cbi = 0; cbi < 8; ++cbi) {
        const int col   = cbi * 16 + n16;
        const int sflag = col & 1;
        const int j     = col >> 1;

        Frag b0, b1;
        {
            const uint4* bp = Wpk + ((size_t)(part * 512 + cbi * 64 + lane)) * 2;
            *(uint4*)&b0 = bp[0];
            *(uint4*)&b1 = bp[1];
        }
        float bias = 0.0f;
        if (part == 0) bias = sflag ? bs[j] : bf[j];

        floatx4 acc = {bias, bias, bias, bias};
        acc = __builtin_amdgcn_mfma_f32_16x16x32_bf16(a0.s, b0.s, acc, 0, 0, 0);
        acc = __builtin_amdgcn_mfma_f32_16x16x32_bf16(a1.s, b1.s, acc, 0, 0, 0);

#pragma unroll
        for (int r = 0; r < 4; ++r)
            L[(quad * 4 + r) * NSTR + col] = bf16_1(acc[r]);
    }

#pragma unroll
    for (int it = 0; it < 4; ++it) {
        const int node_l = it * 4 + quad;
        const int c8     = n16 * 8;
        uint4 v = *(const uint4*)(L + node_l * NSTR + c8);
        *(uint4*)(Tout + (size_t)(ntile * 16 + node_l) * 128 + c8) = v;
    }
}

// ---- node transform (standalone, layer 2) ---------------------------------
__global__ __launch_bounds__(256) void node_transform_mfma(
    const float* __restrict__ H,
    const float* __restrict__ bf,
    const float* __restrict__ bs,
    const uint4* __restrict__ Wpk,
    unsigned short* __restrict__ Tdst,
    unsigned short* __restrict__ Tsrc,
    float* __restrict__ hinit)
{
    __shared__ unsigned short lt[4][16 * NSTR];
    const int lane = threadIdx.x & 63;
    const int wid  = threadIdx.x >> 6;
    const int n16  = lane & 15;
    const int quad = lane >> 4;
    const int kc   = quad * 8;
    unsigned short* L = lt[wid];

    const int gid = blockIdx.x * 4 + wid;
    const int NW  = (N_NODES / 16) * 2;
    if (gid >= NW) return;
    const int ntile = gid >> 1;
    const int part  = gid & 1;
    unsigned short* Tout = part ? Tsrc : Tdst;

    const float* hrow = H + (size_t)(ntile * 16 + n16) * D;
    float4 q0 = *(const float4*)(hrow + kc);
    float4 q1 = *(const float4*)(hrow + kc + 4);
    float4 q2 = *(const float4*)(hrow + 32 + kc);
    float4 q3 = *(const float4*)(hrow + 32 + kc + 4);
    Frag a0, a1;
    a0.u[0] = pk_bf16(q0.x, q0.y); a0.u[1] = pk_bf16(q0.z, q0.w);
    a0.u[2] = pk_bf16(q1.x, q1.y); a0.u[3] = pk_bf16(q1.z, q1.w);
    a1.u[0] = pk_bf16(q2.x, q2.y); a1.u[1] = pk_bf16(q2.z, q2.w);
    a1.u[2] = pk_bf16(q3.x, q3.y); a1.u[3] = pk_bf16(q3.z, q3.w);

    if (part == 0) {
        float4* hp = (float4*)(hinit + (size_t)(ntile * 16 + n16) * D);
        hp[quad * 2]     = q0;
        hp[quad * 2 + 1] = q1;
        hp[8 + quad * 2] = q2;
        hp[9 + quad * 2] = q3;
    }

#pragma unroll
    for (int cbi = 0; cbi < 8; ++cbi) {
        const int col   = cbi * 16 + n16;
        const int sflag = col & 1;
        const int j     = col >> 1;

        Frag b0, b1;
        {
            const uint4* bp = Wpk + ((size_t)(part * 512 + cbi * 64 + lane)) * 2;
            *(uint4*)&b0 = bp[0];
            *(uint4*)&b1 = bp[1];
        }
        float bias = 0.0f;
        if (part == 0) bias = sflag ? bs[j] : bf[j];

        floatx4 acc = {bias, bias, bias, bias};
        acc = __builtin_amdgcn_mfma_f32_16x16x32_bf16(a0.s, b0.s, acc, 0, 0, 0);
        acc = __builtin_amdgcn_mfma_f32_16x16x32_bf16(a1.s, b1.s, acc, 0, 0, 0);

#pragma unroll
        for (int r = 0; r < 4; ++r)
            L[(quad * 4 + r) * NSTR + col] = bf16_1(acc[r]);
    }

#pragma unroll
    for (int it = 0; it < 4; ++it) {
        const int node_l = it * 4 + quad;
        const int c8     = n16 * 8;
        uint4 v = *(const uint4*)(L + node_l * NSTR + c8);
        *(uint4*)(Tout + (size_t)(ntile * 16 + node_l) * 128 + c8) = v;
    }
}

// ---- edge kernel: 64 edges/wave, dbuf gathers, hoisted dst unpack ---------
__global__ __launch_bounds__(256) void edge_message_mfma(
    const unsigned short* __restrict__ Tdst,  // [N_NODES][128] bf16
    const unsigned short* __restrict__ Tsrc,  // [N_NODES][128] bf16
    const unsigned short* __restrict__ eaS,   // [N_EDGES][32] bf16, sorted
    const int2* __restrict__ sd_sorted,       // [N_EDGES] (src,dst) sorted
    const uint4* __restrict__ WpkE,           // this layer's edge fragments
    float* __restrict__ hout)                 // [N_NODES][64], pre-init = hin
{
    const int lane = threadIdx.x & 63;
    const int wid  = threadIdx.x >> 6;
    const int n16  = lane & 15;
    const int quad = lane >> 4;
    const int c0   = quad * 8;

    Frag bfr[4], bsr[4];
#pragma unroll
    for (int jb = 0; jb < 4; ++jb) {
        *(uint4*)&bfr[jb] = WpkE[((size_t)(jb * 64 + lane)) * 2 + 0];
        *(uint4*)&bsr[jb] = WpkE[((size_t)(jb * 64 + lane)) * 2 + 1];
    }

    // bijective XCD swizzle (nwg = 3125, q = 390, rr = 5)
    const int nwg = gridDim.x;
    const int xcd = blockIdx.x & 7;
    const int idx = blockIdx.x >> 3;
    const int q   = nwg >> 3, rr = nwg & 7;
    const int sb  = (xcd < rr ? xcd * (q + 1) : rr * (q + 1) + (xcd - rr) * q) + idx;
    const int w   = sb * 4 + wid;            // wave slot 0..12499
    const int base = w * 64;                 // 64 consecutive edges

    const floatx4 zero = {0.0f, 0.0f, 0.0f, 0.0f};

    // 16 sd upfront (quad-uniform, 8x int4)
    const int4* sdp4 = (const int4*)(sd_sorted + base + quad * 16);
    int4 sdq[8];
#pragma unroll
    for (int i = 0; i < 8; ++i) sdq[i] = sdp4[i];

#define SV(e) ((((e) & 1) != 0) ? sdq[(e) >> 1].z : sdq[(e) >> 1].x)
#define DV(e) ((((e) & 1) != 0) ? sdq[(e) >> 1].w : sdq[(e) >> 1].y)

    const unsigned short* aptr =
        eaS + (size_t)(base + (n16 >> 2) * 16 + (n16 & 3)) * 32 + c0;
    Frag af;
    af.s = *(const short8*)aptr;

    // src-row double buffer: [buf][r][jb], static indices after unroll
    unsigned sbuf[2][4][4];
#pragma unroll
    for (int r = 0; r < 4; ++r) {
        const unsigned* srow = (const unsigned*)(Tsrc + (size_t)SV(r) * 128);
        sbuf[0][r][0] = srow[n16];
        sbuf[0][r][1] = srow[16 + n16];
        sbuf[0][r][2] = srow[32 + n16];
        sbuf[0][r][3] = srow[48 + n16];
    }

    // per-quad run-length state; dst unpacked once per run
    int cur_d = -1;
    float dfl0 = 0.f, dfl1 = 0.f, dfl2 = 0.f, dfl3 = 0.f;
    float dfh0 = 0.f, dfh1 = 0.f, dfh2 = 0.f, dfh3 = 0.f;
    float acc0 = 0.f, acc1 = 0.f, acc2 = 0.f, acc3 = 0.f;

#pragma unroll
    for (int tt = 0; tt < 4; ++tt) {
        const int cb = tt & 1, nb = cb ^ 1;
        if (tt < 3) {
#pragma unroll
            for (int r = 0; r < 4; ++r) {
                const unsigned* srow =
                    (const unsigned*)(Tsrc + (size_t)SV(4 * (tt + 1) + r) * 128);
                sbuf[nb][r][0] = srow[n16];
                sbuf[nb][r][1] = srow[16 + n16];
                sbuf[nb][r][2] = srow[32 + n16];
                sbuf[nb][r][3] = srow[48 + n16];
            }
        }

        floatx4 accf[4], accs[4];
#pragma unroll
        for (int jb = 0; jb < 4; ++jb) {
            accf[jb] = __builtin_amdgcn_mfma_f32_16x16x32_bf16(af.s, bfr[jb].s, zero, 0, 0, 0);
            accs[jb] = __builtin_amdgcn_mfma_f32_16x16x32_bf16(af.s, bsr[jb].s, zero, 0, 0, 0);
        }
        if (tt < 3) af.s = *(const short8*)(aptr + (tt + 1) * 128);

#pragma unroll
        for (int r = 0; r < 4; ++r) {
            const int dv = DV(4 * tt + r);
            if (dv != cur_d) {
                if (cur_d >= 0) {
                    float* hp = hout + (size_t)cur_d * D + n16;
                    atomicAdd(hp +  0, acc0);     // 16 lanes contiguous 64B
                    atomicAdd(hp + 16, acc1);
                    atomicAdd(hp + 32, acc2);
                    atomicAdd(hp + 48, acc3);
                }
                cur_d = dv;
                const unsigned* drow = (const unsigned*)(Tdst + (size_t)dv * 128);
                unsigned t0 = drow[n16];
                unsigned t1 = drow[16 + n16];
                unsigned t2 = drow[32 + n16];
                unsigned t3 = drow[48 + n16];
                dfl0 = upk(t0 & 0xFFFFu); dfh0 = upk(t0 >> 16);
                dfl1 = upk(t1 & 0xFFFFu); dfh1 = upk(t1 >> 16);
                dfl2 = upk(t2 & 0xFFFFu); dfh2 = upk(t2 >> 16);
                dfl3 = upk(t3 & 0xFFFFu); dfh3 = upk(t3 >> 16);
                acc0 = acc1 = acc2 = acc3 = 0.f;
            }
#pragma unroll
            for (int jb = 0; jb < 4; ++jb) {
                float dl = (jb == 0) ? dfl0 : (jb == 1) ? dfl1 : (jb == 2) ? dfl2 : dfl3;
                float dh = (jb == 0) ? dfh0 : (jb == 1) ? dfh1 : (jb == 2) ? dfh2 : dfh3;
                unsigned sv = sbuf[cb][r][jb];
                float vf = accf[jb][r] + dl + upk(sv & 0xFFFFu);
                float vs = accs[jb][r] + dh + upk(sv >> 16);
                float sig = __builtin_amdgcn_rcpf(1.0f + __expf(-vf));
                float spl = fmaxf(vs, 0.0f) + __logf(1.0f + __expf(-fabsf(vs)));
                float msg = sig * spl;
                if      (jb == 0) acc0 += msg;
                else if (jb == 1) acc1 += msg;
                else if (jb == 2) acc2 += msg;
                else              acc3 += msg;
            }
        }
    }
#undef SV
#undef DV
    // final flush (cur_d always valid here)
    {
        float* hp = hout + (size_t)cur_d * D + n16;
        atomicAdd(hp +  0, acc0);
        atomicAdd(hp + 16, acc1);
        atomicAdd(hp + 32, acc2);
        atomicAdd(hp + 48, acc3);
    }
}

// segment_sum(h, batch) into pooled[N_GRAPHS][64]
__global__ __launch_bounds__(256) void pool_kernel(
    const float* __restrict__ h,
    const int* __restrict__ batch,
    float* __restrict__ pooled)
{
    const int lane = threadIdx.x & 63;
    const int wid  = threadIdx.x >> 6;
    const int w = blockIdx.x * 4 + wid;
    const int n0 = w * 16;
    if (n0 >= N_NODES) return;
    const int nend = (n0 + 16 < N_NODES) ? (n0 + 16) : N_NODES;

    int cur = batch[n0];
    float acc = 0.0f;
    for (int n = n0; n < nend; ++n) {
        int b = batch[n];                      // wave-uniform scalar load
        float v = h[(size_t)n * D + lane];
        if (b != cur) {
            atomicAdd(&pooled[(size_t)cur * D + lane], acc);
            cur = b; acc = v;
        } else {
            acc += v;
        }
    }
    atomicAdd(&pooled[(size_t)cur * D + lane], acc);
}

__global__ __launch_bounds__(256) void out_kernel(
    const float* __restrict__ pooled,
    const float* __restrict__ Wout,
    const float* __restrict__ bout,
    float* __restrict__ out)
{
    const int g = blockIdx.x * blockDim.x + threadIdx.x;
    if (g >= N_GRAPHS) return;
    float acc = bout[0];
#pragma unroll
    for (int j = 0; j < D; ++j) acc = fmaf(pooled[(size_t)g * D + j], Wout[j], acc);
    out[g] = acc;
}

extern "C" void kernel_launch(void* const* d_in, const int* in_sizes, int n_in,
                              void* d_out, int out_size, void* d_ws, size_t ws_size,
                              hipStream_t stream) {
    const float* x     = (const float*)d_in[0];
    const int*   ei    = (const int*)  d_in[1];
    const float* ea    = (const float*)d_in[2];
    const int*   batch = (const int*)  d_in[3];
    const float* Wf1   = (const float*)d_in[4];
    const float* bf1   = (const float*)d_in[5];
    const float* Ws1   = (const float*)d_in[6];
    const float* bs1   = (const float*)d_in[7];
    const float* Wf2   = (const float*)d_in[8];
    const float* bf2   = (const float*)d_in[9];
    const float* Ws2   = (const float*)d_in[10];
    const float* bs2   = (const float*)d_in[11];
    const float* Wout  = (const float*)d_in[12];
    const float* bout  = (const float*)d_in[13];
    float* out = (float*)d_out;

    // workspace carve (~116 MB)
    char* base = (char*)d_ws;
    size_t o = 0;
    unsigned short* Tdst = (unsigned short*)(base + o); o += (size_t)N_NODES * 128 * 2;
    unsigned short* Tsrc = (unsigned short*)(base + o); o += (size_t)N_NODES * 128 * 2;
    unsigned short* eaS  = (unsigned short*)(base + o); o += (size_t)N_EDGES * 32 * 2;
    float* h1     = (float*)(base + o); o += (size_t)N_NODES * D * 4;
    float* h2     = (float*)(base + o); o += (size_t)N_NODES * D * 4;
    float* pooled = (float*)(base + o); o += (size_t)N_GRAPHS * D * 4;
    int* deg8 = (int*)(base + o); o += (size_t)8 * N_NODES * 4;
    int* off  = (int*)(base + o); o += (size_t)(N_NODES + 1) * 4;
    int* off8 = (int*)(base + o); o += (size_t)8 * N_NODES * 4;
    int* tsum = (int*)(base + o); o += 256 * 4;
    int2* sd_sorted = (int2*)(base + o); o += (size_t)N_EDGES * 8;
    int* r8 = (int*)(base + o); o += (size_t)N_EDGES * 4;
    uint4* WpkNT = (uint4*)(base + o); o += (size_t)2 * 1024 * 2 * 16;
    uint4* WpkE  = (uint4*)(base + o); o += (size_t)2 * 256 * 2 * 16;

    // 1. pack_W + zero(deg8) + zero(pooled)
    setup_kernel<<<1701, 256, 0, stream>>>(Wf1, Ws1, Wf2, Ws2,
                                           WpkNT, WpkE, deg8, pooled);
    // 2. hist (8-way sub-histogram + sub-rank)
    hist_kernel<<<NB_SCAT, 256, 0, stream>>>(ei, deg8, r8);
    // 3-4. scan
    scan1<<<NB_SCAN, 256, 0, stream>>>(deg8, off, tsum);
    scan23<<<NB_SCAN, 256, 0, stream>>>(off, tsum, deg8, off8);
    // 5. fused scatter_pack + node_transform L1 (writes h1 = x)
    fused_scatter_nt<<<NB_FUSED, 256, 0, stream>>>(
        ei, off8, r8, ea, eaS, sd_sorted,
        x, bf1, bs1, WpkNT, Tdst, Tsrc, h1);
    // 6. layer 1 edge (flush -> h1)
    edge_message_mfma<<<NB_SCAT, 256, 0, stream>>>(Tdst, Tsrc, eaS, sd_sorted,
                                                   WpkE, h1);
    // 7. layer 2 node transform (writes h2 = h1)
    node_transform_mfma<<<1563, 256, 0, stream>>>(h1, bf2, bs2, WpkNT + 2048,
                                                  Tdst, Tsrc, h2);
    // 8. layer 2 edge (flush -> h2)
    edge_message_mfma<<<NB_SCAT, 256, 0, stream>>>(Tdst, Tsrc, eaS, sd_sorted,
                                                   WpkE + 512, h2);
    // 9. pool + 10. out
    pool_kernel<<<782, 256, 0, stream>>>(h2, batch, pooled);
    out_kernel<<<2, 256, 0, stream>>>(pooled, Wout, bout, out);
}

// Round 15
// 437.898 us; speedup vs baseline: 1.2527x; 1.0045x over previous
//
#include <hip/hip_runtime.h>
#include <math.h>

#define N_NODES 50000
#define N_EDGES 800000
#define N_GRAPHS 512
#define D 64
#define DE 32
#define NB_SCAN 196            // ceil(50000/256)
#define NSTR 136               // NT LDS row stride (ushorts), 272B = 16B-aligned
#define NB_SCAT 3125           // scatter blocks (800K/256)
#define NB_FUSED 4689          // 3 * 1563: role = blockIdx % 3 (2 -> NT)

// ---------------------------------------------------------------------------
// R23 (on R22's 439.9): two random-traffic cuts + one overlap.
//  * dst is CSR-derivable: scan23 fills dst_fill[pos]=n SEQUENTIALLY (6.4MB
//    streaming); scatter stores only src (4B/edge random, was 8B int2) ->
//    sd-class random lines ~53->~41MB.
//  * hist_combo: hist || pack_W || pooled-zero in one launch (hist is
//    latency-bound at 5% VALU; pack/zero ride free). setup = deg8-zero only.
// Model: four ~90us kernels all pinned at 2.0-2.3 TB/s effective random-line
// BW, VALU ~5% -> machinery plateau; this round tests the last line-count
// levers.
// Laws: R21 NT-stores only full-line streaming; R17 atomics need line-spread;
// R14 flush = 4 atomics x 16 lanes contiguous 64B; R19 permutation paid once
// on write side; R22 hist bound by transaction count not line conflicts.
//
// MFMA 16x16x32 bf16 fragment maps (m89/m120-verified):
//   A[m][k]: m = lane&15, k = (lane>>4)*8 + i
//   B[k][n]: n = lane&15, k = (lane>>4)*8 + i
//   C/D    : col n = lane&15, row m = (lane>>4)*4 + reg
// Edge A-row permutation: row m of MFMA tt <- edge base + 16*(m>>2)+(m&3)+4tt
//   => quad q processes edges base+16q .. base+16q+15 IN ORDER.
// Edge column map: j = 16*jb + n16 (contiguous-flush).
// ---------------------------------------------------------------------------

typedef __attribute__((ext_vector_type(8))) short short8;
typedef __attribute__((ext_vector_type(4))) float floatx4;
union Frag { short8 s; unsigned u[4]; };
union U4   { uint4 v; unsigned u[4]; };

__device__ inline unsigned pk_bf16(float lo, float hi) {
    unsigned a = __float_as_uint(lo);
    unsigned b = __float_as_uint(hi);
    a = (a + 0x7FFFu + ((a >> 16) & 1u)) >> 16;
    b = (b + 0x7FFFu + ((b >> 16) & 1u)) >> 16;
    return a | (b << 16);
}
__device__ inline unsigned short bf16_1(float v) {
    unsigned a = __float_as_uint(v);
    return (unsigned short)((a + 0x7FFFu + ((a >> 16) & 1u)) >> 16);
}
__device__ inline float upk(unsigned u16) { return __uint_as_float(u16 << 16); }

// ---- setup: zero deg8 only --------------------------------------------------
__global__ __launch_bounds__(256) void setup_zero(int* __restrict__ deg8)
{
    int i = blockIdx.x * 256 + threadIdx.x;
    if (i < 8 * N_NODES) deg8[i] = 0;
}

// ---- hist_combo: hist (0..3124) || pack_W (3125..3134) || zero pooled -----
__global__ __launch_bounds__(256) void hist_combo(
    const int* __restrict__ ei, int* __restrict__ deg8, int* __restrict__ r8,
    const float* __restrict__ Wf1, const float* __restrict__ Ws1,
    const float* __restrict__ Wf2, const float* __restrict__ Ws2,
    uint4* __restrict__ WpkNT, uint4* __restrict__ WpkE,
    float* __restrict__ pooled)
{
    const int b = blockIdx.x;
    if (b < NB_SCAT) {
        const int sub = b & 7;
        int e = b * 256 + threadIdx.x;
        r8[e] = atomicAdd(&deg8[sub * N_NODES + ei[N_EDGES + e]], 1);
        return;
    }
    if (b >= NB_SCAT + 10) {              // zero pooled: 128 blocks
        int i = (b - NB_SCAT - 10) * 256 + threadIdx.x;
        if (i < N_GRAPHS * D) pooled[i] = 0.0f;
        return;
    }
    // pack_W: 10 blocks
    const int pb = b - NB_SCAT;
    const int layer = pb / 5;
    const float* Wf = layer ? Wf2 : Wf1;
    const float* Ws = layer ? Ws2 : Ws1;
    const int i = (pb % 5) * 256 + threadIdx.x;   // 0..1279
    if (i < 1024) {
        const int p    = i >> 9;
        const int cbi  = (i >> 6) & 7;
        const int l    = i & 63;
        const int n16  = l & 15, quad = l >> 4, kc = quad * 8;
        const int col  = cbi * 16 + n16;
        const int j    = col >> 1;
        const float* Wsel = (col & 1) ? Ws : Wf;
        const int rbase = p * 64;
        U4 b0, b1;
#pragma unroll
        for (int pp = 0; pp < 4; ++pp) {
            b0.u[pp] = pk_bf16(Wsel[(rbase + kc + 2 * pp) * 64 + j],
                               Wsel[(rbase + kc + 2 * pp + 1) * 64 + j]);
            b1.u[pp] = pk_bf16(Wsel[(rbase + 32 + kc + 2 * pp) * 64 + j],
                               Wsel[(rbase + 32 + kc + 2 * pp + 1) * 64 + j]);
        }
        uint4* o = WpkNT + ((size_t)layer * 1024 + i) * 2;
        o[0] = b0.v; o[1] = b1.v;
    } else if (i < 1280) {
        const int k  = i - 1024;
        const int jb = k >> 6;
        const int l  = k & 63;
        const int n16 = l & 15, quad = l >> 4, c0 = quad * 8;
        const int j = jb * 16 + n16;             // contiguous-flush map
        U4 bf_, bs_;
#pragma unroll
        for (int pp = 0; pp < 4; ++pp) {
            bf_.u[pp] = pk_bf16(Wf[(128 + c0 + 2 * pp) * 64 + j],
                                Wf[(128 + c0 + 2 * pp + 1) * 64 + j]);
            bs_.u[pp] = pk_bf16(Ws[(128 + c0 + 2 * pp) * 64 + j],
                                Ws[(128 + c0 + 2 * pp + 1) * 64 + j]);
        }
        uint4* o = WpkE + ((size_t)layer * 256 + k) * 2;
        o[0] = bf_.v; o[1] = bs_.v;
    }
}

// scan1: total degree per node (sum of 8 subs) -> block-local prefix
__global__ __launch_bounds__(256) void scan1(
    const int* __restrict__ deg8, int* __restrict__ off, int* __restrict__ tsum)
{
    __shared__ int s[256];
    int i = blockIdx.x * 256 + threadIdx.x;
    int tot = 0;
    if (i < N_NODES) {
#pragma unroll
        for (int ss = 0; ss < 8; ++ss) tot += deg8[ss * N_NODES + i];
    }
    s[threadIdx.x] = tot;
    __syncthreads();
    if (threadIdx.x == 0) {
        int run = 0;
        for (int k = 0; k < 256; ++k) { int t = s[k]; s[k] = run; run += t; }
        tsum[blockIdx.x] = run;
    }
    __syncthreads();
    if (i < N_NODES) off[i] = s[threadIdx.x];
}

// scan23: cross-block prefix + absolute per-sub offsets + SEQUENTIAL dst fill
__global__ __launch_bounds__(256) void scan23(
    const int* __restrict__ off, const int* __restrict__ tsum,
    const int* __restrict__ deg8, int* __restrict__ off8,
    int* __restrict__ dst_fill)
{
    __shared__ int pfx;
    if (threadIdx.x == 0) {
        int run = 0;
        for (int k = 0; k < (int)blockIdx.x; ++k) run += tsum[k];
        pfx = run;
    }
    __syncthreads();
    int i = blockIdx.x * 256 + threadIdx.x;
    if (i < N_NODES) {
        int start = off[i] + pfx;
        int running = start;
#pragma unroll
        for (int ss = 0; ss < 8; ++ss) {
            off8[ss * N_NODES + i] = running;
            running += deg8[ss * N_NODES + i];
        }
        // dst at sorted position is CSR-derivable: fill [start, running)
        for (int p = start; p < running; ++p) dst_fill[p] = i;
    }
}

// ---- FUSED: scatter_pack + node_transform L1, roles INTERLEAVED -----------
// blockIdx % 3 == 2 -> NT (1563 blocks); else scatter (3126 slots, 3125 used)
__global__ __launch_bounds__(256) void fused_scatter_nt(
    const int* __restrict__ ei, const int* __restrict__ off8,
    const int* __restrict__ r8, const float* __restrict__ ea,
    unsigned short* __restrict__ eaS, int* __restrict__ src_sorted,
    const float* __restrict__ H,
    const float* __restrict__ bf, const float* __restrict__ bs,
    const uint4* __restrict__ Wpk,
    unsigned short* __restrict__ Tdst, unsigned short* __restrict__ Tsrc,
    float* __restrict__ hinit)
{
    __shared__ unsigned short lt[4][16 * NSTR];
    const int k = blockIdx.x;

    if ((k % 3) != 2) {
        const int sid = k - (k / 3);         // 0..3125; enumerates edge blocks
        if (sid >= NB_SCAT) return;
        const int sub = sid & 7;             // SAME map as hist (block b&7)
        int e = sid * 256 + threadIdx.x;
        int s = ei[e];
        int d = ei[N_EDGES + e];
        int pos = off8[sub * N_NODES + d] + r8[e];
        src_sorted[pos] = s;                 // 4B random (dst not stored)

        const float4* src4 = (const float4*)(ea + (size_t)e * 32);
        uint4* dst16 = (uint4*)(eaS + (size_t)pos * 32);
#pragma unroll
        for (int q = 0; q < 2; ++q) {
            float4 v0 = src4[4 * q + 0];
            float4 v1 = src4[4 * q + 1];
            float4 v2 = src4[4 * q + 2];
            float4 v3 = src4[4 * q + 3];
            uint4 o0;
            o0.x = pk_bf16(v0.x, v0.y); o0.y = pk_bf16(v0.z, v0.w);
            o0.z = pk_bf16(v1.x, v1.y); o0.w = pk_bf16(v1.z, v1.w);
            uint4 o1;
            o1.x = pk_bf16(v2.x, v2.y); o1.y = pk_bf16(v2.z, v2.w);
            o1.z = pk_bf16(v3.x, v3.y); o1.w = pk_bf16(v3.z, v3.w);
            dst16[2 * q + 0] = o0;
            dst16[2 * q + 1] = o1;
        }
        return;
    }

    const int lane = threadIdx.x & 63;
    const int wid  = threadIdx.x >> 6;
    const int n16  = lane & 15;
    const int quad = lane >> 4;
    const int kc   = quad * 8;
    unsigned short* L = lt[wid];

    const int gid = (k / 3) * 4 + wid;
    const int NW  = (N_NODES / 16) * 2;
    if (gid >= NW) return;
    const int ntile = gid >> 1;
    const int part  = gid & 1;
    unsigned short* Tout = part ? Tsrc : Tdst;

    const float* hrow = H + (size_t)(ntile * 16 + n16) * D;
    float4 q0 = *(const float4*)(hrow + kc);
    float4 q1 = *(const float4*)(hrow + kc + 4);
    float4 q2 = *(const float4*)(hrow + 32 + kc);
    float4 q3 = *(const float4*)(hrow + 32 + kc + 4);
    Frag a0, a1;
    a0.u[0] = pk_bf16(q0.x, q0.y); a0.u[1] = pk_bf16(q0.z, q0.w);
    a0.u[2] = pk_bf16(q1.x, q1.y); a0.u[3] = pk_bf16(q1.z, q1.w);
    a1.u[0] = pk_bf16(q2.x, q2.y); a1.u[1] = pk_bf16(q2.z, q2.w);
    a1.u[2] = pk_bf16(q3.x, q3.y); a1.u[3] = pk_bf16(q3.z, q3.w);

    if (part == 0) {
        float4* hp = (float4*)(hinit + (size_t)(ntile * 16 + n16) * D);
        hp[quad * 2]     = q0;
        hp[quad * 2 + 1] = q1;
        hp[8 + quad * 2] = q2;
        hp[9 + quad * 2] = q3;
    }

#pragma unroll
    for (int cbi = 0; cbi < 8; ++cbi) {
        const int col   = cbi * 16 + n16;
        const int sflag = col & 1;
        const int j     = col >> 1;

        Frag b0, b1;
        {
            const uint4* bp = Wpk + ((size_t)(part * 512 + cbi * 64 + lane)) * 2;
            *(uint4*)&b0 = bp[0];
            *(uint4*)&b1 = bp[1];
        }
        float bias = 0.0f;
        if (part == 0) bias = sflag ? bs[j] : bf[j];

        floatx4 acc = {bias, bias, bias, bias};
        acc = __builtin_amdgcn_mfma_f32_16x16x32_bf16(a0.s, b0.s, acc, 0, 0, 0);
        acc = __builtin_amdgcn_mfma_f32_16x16x32_bf16(a1.s, b1.s, acc, 0, 0, 0);

#pragma unroll
        for (int r = 0; r < 4; ++r)
            L[(quad * 4 + r) * NSTR + col] = bf16_1(acc[r]);
    }

#pragma unroll
    for (int it = 0; it < 4; ++it) {
        const int node_l = it * 4 + quad;
        const int c8     = n16 * 8;
        uint4 v = *(const uint4*)(L + node_l * NSTR + c8);
        *(uint4*)(Tout + (size_t)(ntile * 16 + node_l) * 128 + c8) = v;
    }
}

// ---- node transform (standalone, layer 2) ---------------------------------
__global__ __launch_bounds__(256) void node_transform_mfma(
    const float* __restrict__ H,
    const float* __restrict__ bf,
    const float* __restrict__ bs,
    const uint4* __restrict__ Wpk,
    unsigned short* __restrict__ Tdst,
    unsigned short* __restrict__ Tsrc,
    float* __restrict__ hinit)
{
    __shared__ unsigned short lt[4][16 * NSTR];
    const int lane = threadIdx.x & 63;
    const int wid  = threadIdx.x >> 6;
    const int n16  = lane & 15;
    const int quad = lane >> 4;
    const int kc   = quad * 8;
    unsigned short* L = lt[wid];

    const int gid = blockIdx.x * 4 + wid;
    const int NW  = (N_NODES / 16) * 2;
    if (gid >= NW) return;
    const int ntile = gid >> 1;
    const int part  = gid & 1;
    unsigned short* Tout = part ? Tsrc : Tdst;

    const float* hrow = H + (size_t)(ntile * 16 + n16) * D;
    float4 q0 = *(const float4*)(hrow + kc);
    float4 q1 = *(const float4*)(hrow + kc + 4);
    float4 q2 = *(const float4*)(hrow + 32 + kc);
    float4 q3 = *(const float4*)(hrow + 32 + kc + 4);
    Frag a0, a1;
    a0.u[0] = pk_bf16(q0.x, q0.y); a0.u[1] = pk_bf16(q0.z, q0.w);
    a0.u[2] = pk_bf16(q1.x, q1.y); a0.u[3] = pk_bf16(q1.z, q1.w);
    a1.u[0] = pk_bf16(q2.x, q2.y); a1.u[1] = pk_bf16(q2.z, q2.w);
    a1.u[2] = pk_bf16(q3.x, q3.y); a1.u[3] = pk_bf16(q3.z, q3.w);

    if (part == 0) {
        float4* hp = (float4*)(hinit + (size_t)(ntile * 16 + n16) * D);
        hp[quad * 2]     = q0;
        hp[quad * 2 + 1] = q1;
        hp[8 + quad * 2] = q2;
        hp[9 + quad * 2] = q3;
    }

#pragma unroll
    for (int cbi = 0; cbi < 8; ++cbi) {
        const int col   = cbi * 16 + n16;
        const int sflag = col & 1;
        const int j     = col >> 1;

        Frag b0, b1;
        {
            const uint4* bp = Wpk + ((size_t)(part * 512 + cbi * 64 + lane)) * 2;
            *(uint4*)&b0 = bp[0];
            *(uint4*)&b1 = bp[1];
        }
        float bias = 0.0f;
        if (part == 0) bias = sflag ? bs[j] : bf[j];

        floatx4 acc = {bias, bias, bias, bias};
        acc = __builtin_amdgcn_mfma_f32_16x16x32_bf16(a0.s, b0.s, acc, 0, 0, 0);
        acc = __builtin_amdgcn_mfma_f32_16x16x32_bf16(a1.s, b1.s, acc, 0, 0, 0);

#pragma unroll
        for (int r = 0; r < 4; ++r)
            L[(quad * 4 + r) * NSTR + col] = bf16_1(acc[r]);
    }

#pragma unroll
    for (int it = 0; it < 4; ++it) {
        const int node_l = it * 4 + quad;
        const int c8     = n16 * 8;
        uint4 v = *(const uint4*)(L + node_l * NSTR + c8);
        *(uint4*)(Tout + (size_t)(ntile * 16 + node_l) * 128 + c8) = v;
    }
}

// ---- edge kernel: 64 edges/wave, dbuf gathers, hoisted dst unpack ---------
__global__ __launch_bounds__(256) void edge_message_mfma(
    const unsigned short* __restrict__ Tdst,  // [N_NODES][128] bf16
    const unsigned short* __restrict__ Tsrc,  // [N_NODES][128] bf16
    const unsigned short* __restrict__ eaS,   // [N_EDGES][32] bf16, sorted
    const int* __restrict__ src_sorted,       // [N_EDGES] src, sorted
    const int* __restrict__ dst_fill,         // [N_EDGES] dst, sorted (CSR)
    const uint4* __restrict__ WpkE,           // this layer's edge fragments
    float* __restrict__ hout)                 // [N_NODES][64], pre-init = hin
{
    const int lane = threadIdx.x & 63;
    const int wid  = threadIdx.x >> 6;
    const int n16  = lane & 15;
    const int quad = lane >> 4;
    const int c0   = quad * 8;

    Frag bfr[4], bsr[4];
#pragma unroll
    for (int jb = 0; jb < 4; ++jb) {
        *(uint4*)&bfr[jb] = WpkE[((size_t)(jb * 64 + lane)) * 2 + 0];
        *(uint4*)&bsr[jb] = WpkE[((size_t)(jb * 64 + lane)) * 2 + 1];
    }

    // bijective XCD swizzle (nwg = 3125, q = 390, rr = 5)
    const int nwg = gridDim.x;
    const int xcd = blockIdx.x & 7;
    const int idx = blockIdx.x >> 3;
    const int q   = nwg >> 3, rr = nwg & 7;
    const int sb  = (xcd < rr ? xcd * (q + 1) : rr * (q + 1) + (xcd - rr) * q) + idx;
    const int w   = sb * 4 + wid;            // wave slot 0..12499
    const int base = w * 64;                 // 64 consecutive edges

    const floatx4 zero = {0.0f, 0.0f, 0.0f, 0.0f};

    // 16 src + 16 dst upfront (quad-uniform, 4x int4 each)
    const int4* sp4 = (const int4*)(src_sorted + base + quad * 16);
    const int4* dp4 = (const int4*)(dst_fill + base + quad * 16);
    int4 sq[4], dq[4];
#pragma unroll
    for (int i = 0; i < 4; ++i) { sq[i] = sp4[i]; dq[i] = dp4[i]; }

#define SV(e) (((e) & 3) == 0 ? sq[(e) >> 2].x : ((e) & 3) == 1 ? sq[(e) >> 2].y \
             : ((e) & 3) == 2 ? sq[(e) >> 2].z : sq[(e) >> 2].w)
#define DV(e) (((e) & 3) == 0 ? dq[(e) >> 2].x : ((e) & 3) == 1 ? dq[(e) >> 2].y \
             : ((e) & 3) == 2 ? dq[(e) >> 2].z : dq[(e) >> 2].w)

    const unsigned short* aptr =
        eaS + (size_t)(base + (n16 >> 2) * 16 + (n16 & 3)) * 32 + c0;
    Frag af;
    af.s = *(const short8*)aptr;

    // src-row double buffer: [buf][r][jb], static indices after unroll
    unsigned sbuf[2][4][4];
#pragma unroll
    for (int r = 0; r < 4; ++r) {
        const unsigned* srow = (const unsigned*)(Tsrc + (size_t)SV(r) * 128);
        sbuf[0][r][0] = srow[n16];
        sbuf[0][r][1] = srow[16 + n16];
        sbuf[0][r][2] = srow[32 + n16];
        sbuf[0][r][3] = srow[48 + n16];
    }

    // per-quad run-length state; dst unpacked once per run
    int cur_d = -1;
    float dfl0 = 0.f, dfl1 = 0.f, dfl2 = 0.f, dfl3 = 0.f;
    float dfh0 = 0.f, dfh1 = 0.f, dfh2 = 0.f, dfh3 = 0.f;
    float acc0 = 0.f, acc1 = 0.f, acc2 = 0.f, acc3 = 0.f;

#pragma unroll
    for (int tt = 0; tt < 4; ++tt) {
        const int cb = tt & 1, nb = cb ^ 1;
        if (tt < 3) {
#pragma unroll
            for (int r = 0; r < 4; ++r) {
                const unsigned* srow =
                    (const unsigned*)(Tsrc + (size_t)SV(4 * (tt + 1) + r) * 128);
                sbuf[nb][r][0] = srow[n16];
                sbuf[nb][r][1] = srow[16 + n16];
                sbuf[nb][r][2] = srow[32 + n16];
                sbuf[nb][r][3] = srow[48 + n16];
            }
        }

        floatx4 accf[4], accs[4];
#pragma unroll
        for (int jb = 0; jb < 4; ++jb) {
            accf[jb] = __builtin_amdgcn_mfma_f32_16x16x32_bf16(af.s, bfr[jb].s, zero, 0, 0, 0);
            accs[jb] = __builtin_amdgcn_mfma_f32_16x16x32_bf16(af.s, bsr[jb].s, zero, 0, 0, 0);
        }
        if (tt < 3) af.s = *(const short8*)(aptr + (tt + 1) * 128);

#pragma unroll
        for (int r = 0; r < 4; ++r) {
            const int dv = DV(4 * tt + r);
            if (dv != cur_d) {
                if (cur_d >= 0) {
                    float* hp = hout + (size_t)cur_d * D + n16;
                    atomicAdd(hp +  0, acc0);     // 16 lanes contiguous 64B
                    atomicAdd(hp + 16, acc1);
                    atomicAdd(hp + 32, acc2);
                    atomicAdd(hp + 48, acc3);
                }
                cur_d = dv;
                const unsigned* drow = (const unsigned*)(Tdst + (size_t)dv * 128);
                unsigned t0 = drow[n16];
                unsigned t1 = drow[16 + n16];
                unsigned t2 = drow[32 + n16];
                unsigned t3 = drow[48 + n16];
                dfl0 = upk(t0 & 0xFFFFu); dfh0 = upk(t0 >> 16);
                dfl1 = upk(t1 & 0xFFFFu); dfh1 = upk(t1 >> 16);
                dfl2 = upk(t2 & 0xFFFFu); dfh2 = upk(t2 >> 16);
                dfl3 = upk(t3 & 0xFFFFu); dfh3 = upk(t3 >> 16);
                acc0 = acc1 = acc2 = acc3 = 0.f;
            }
#pragma unroll
            for (int jb = 0; jb < 4; ++jb) {
                float dl = (jb == 0) ? dfl0 : (jb == 1) ? dfl1 : (jb == 2) ? dfl2 : dfl3;
                float dh = (jb == 0) ? dfh0 : (jb == 1) ? dfh1 : (jb == 2) ? dfh2 : dfh3;
                unsigned sv = sbuf[cb][r][jb];
                float vf = accf[jb][r] + dl + upk(sv & 0xFFFFu);
                float vs = accs[jb][r] + dh + upk(sv >> 16);
                float sig = __builtin_amdgcn_rcpf(1.0f + __expf(-vf));
                float spl = fmaxf(vs, 0.0f) + __logf(1.0f + __expf(-fabsf(vs)));
                float msg = sig * spl;
                if      (jb == 0) acc0 += msg;
                else if (jb == 1) acc1 += msg;
                else if (jb == 2) acc2 += msg;
                else              acc3 += msg;
            }
        }
    }
#undef SV
#undef DV
    // final flush (cur_d always valid here)
    {
        float* hp = hout + (size_t)cur_d * D + n16;
        atomicAdd(hp +  0, acc0);
        atomicAdd(hp + 16, acc1);
        atomicAdd(hp + 32, acc2);
        atomicAdd(hp + 48, acc3);
    }
}

// segment_sum(h, batch) into pooled[N_GRAPHS][64]
__global__ __launch_bounds__(256) void pool_kernel(
    const float* __restrict__ h,
    const int* __restrict__ batch,
    float* __restrict__ pooled)
{
    const int lane = threadIdx.x & 63;
    const int wid  = threadIdx.x >> 6;
    const int w = blockIdx.x * 4 + wid;
    const int n0 = w * 16;
    if (n0 >= N_NODES) return;
    const int nend = (n0 + 16 < N_NODES) ? (n0 + 16) : N_NODES;

    int cur = batch[n0];
    float acc = 0.0f;
    for (int n = n0; n < nend; ++n) {
        int b = batch[n];                      // wave-uniform scalar load
        float v = h[(size_t)n * D + lane];
        if (b != cur) {
            atomicAdd(&pooled[(size_t)cur * D + lane], acc);
            cur = b; acc = v;
        } else {
            acc += v;
        }
    }
    atomicAdd(&pooled[(size_t)cur * D + lane], acc);
}

__global__ __launch_bounds__(256) void out_kernel(
    const float* __restrict__ pooled,
    const float* __restrict__ Wout,
    const float* __restrict__ bout,
    float* __restrict__ out)
{
    const int g = blockIdx.x * blockDim.x + threadIdx.x;
    if (g >= N_GRAPHS) return;
    float acc = bout[0];
#pragma unroll
    for (int j = 0; j < D; ++j) acc = fmaf(pooled[(size_t)g * D + j], Wout[j], acc);
    out[g] = acc;
}

extern "C" void kernel_launch(void* const* d_in, const int* in_sizes, int n_in,
                              void* d_out, int out_size, void* d_ws, size_t ws_size,
                              hipStream_t stream) {
    const float* x     = (const float*)d_in[0];
    const int*   ei    = (const int*)  d_in[1];
    const float* ea    = (const float*)d_in[2];
    const int*   batch = (const int*)  d_in[3];
    const float* Wf1   = (const float*)d_in[4];
    const float* bf1   = (const float*)d_in[5];
    const float* Ws1   = (const float*)d_in[6];
    const float* bs1   = (const float*)d_in[7];
    const float* Wf2   = (const float*)d_in[8];
    const float* bf2   = (const float*)d_in[9];
    const float* Ws2   = (const float*)d_in[10];
    const float* bs2   = (const float*)d_in[11];
    const float* Wout  = (const float*)d_in[12];
    const float* bout  = (const float*)d_in[13];
    float* out = (float*)d_out;

    // workspace carve (~116 MB)
    char* base = (char*)d_ws;
    size_t o = 0;
    unsigned short* Tdst = (unsigned short*)(base + o); o += (size_t)N_NODES * 128 * 2;
    unsigned short* Tsrc = (unsigned short*)(base + o); o += (size_t)N_NODES * 128 * 2;
    unsigned short* eaS  = (unsigned short*)(base + o); o += (size_t)N_EDGES * 32 * 2;
    float* h1     = (float*)(base + o); o += (size_t)N_NODES * D * 4;
    float* h2     = (float*)(base + o); o += (size_t)N_NODES * D * 4;
    float* pooled = (float*)(base + o); o += (size_t)N_GRAPHS * D * 4;
    int* deg8 = (int*)(base + o); o += (size_t)8 * N_NODES * 4;
    int* off  = (int*)(base + o); o += (size_t)(N_NODES + 1) * 4;
    int* off8 = (int*)(base + o); o += (size_t)8 * N_NODES * 4;
    int* tsum = (int*)(base + o); o += 256 * 4;
    int* src_sorted = (int*)(base + o); o += (size_t)N_EDGES * 4;
    int* dst_fill   = (int*)(base + o); o += (size_t)N_EDGES * 4;
    int* r8 = (int*)(base + o); o += (size_t)N_EDGES * 4;
    uint4* WpkNT = (uint4*)(base + o); o += (size_t)2 * 1024 * 2 * 16;
    uint4* WpkE  = (uint4*)(base + o); o += (size_t)2 * 256 * 2 * 16;

    // 1. zero deg8
    setup_zero<<<1563, 256, 0, stream>>>(deg8);
    // 2. hist || pack_W || zero pooled
    hist_combo<<<NB_SCAT + 10 + 128, 256, 0, stream>>>(
        ei, deg8, r8, Wf1, Ws1, Wf2, Ws2, WpkNT, WpkE, pooled);
    // 3-4. scan (+ sequential dst fill)
    scan1<<<NB_SCAN, 256, 0, stream>>>(deg8, off, tsum);
    scan23<<<NB_SCAN, 256, 0, stream>>>(off, tsum, deg8, off8, dst_fill);
    // 5. fused scatter_pack + node_transform L1 (writes h1 = x)
    fused_scatter_nt<<<NB_FUSED, 256, 0, stream>>>(
        ei, off8, r8, ea, eaS, src_sorted,
        x, bf1, bs1, WpkNT, Tdst, Tsrc, h1);
    // 6. layer 1 edge (flush -> h1)
    edge_message_mfma<<<NB_SCAT, 256, 0, stream>>>(Tdst, Tsrc, eaS,
                                                   src_sorted, dst_fill,
                                                   WpkE, h1);
    // 7. layer 2 node transform (writes h2 = h1)
    node_transform_mfma<<<1563, 256, 0, stream>>>(h1, bf2, bs2, WpkNT + 2048,
                                                  Tdst, Tsrc, h2);
    // 8. layer 2 edge (flush -> h2)
    edge_message_mfma<<<NB_SCAT, 256, 0, stream>>>(Tdst, Tsrc, eaS,
                                                   src_sorted, dst_fill,
                                                   WpkE + 512, h2);
    // 9. pool + 10. out
    pool_kernel<<<782, 256, 0, stream>>>(h2, batch, pooled);
    out_kernel<<<2, 256, 0, stream>>>(pooled, Wout, bout, out);
}